// Round 1
// baseline (1667.956 us; speedup 1.0000x reference)
//
#include <hip/hip_runtime.h>
#include <math.h>

#define HID 128
#define EB 32                 // edges per block
#define NB 32                 // nodes per block
#define IN_STRIDE 260         // 256-wide staging rows, padded (1040 B, 16B-aligned)
#define MS 132                // 128-wide buffers, padded (528 B, 16B-aligned)

__device__ __forceinline__ float fast_tanh(float v) {
    v = fminf(15.0f, fmaxf(-15.0f, v));
    float e = __expf(2.0f * v);
    return (e - 1.0f) / (e + 1.0f);
}

__device__ __forceinline__ float lrelu(float v) {
    return v > 0.0f ? v : 0.01f * v;
}

// Register-blocked tile GEMM: thread t handles cols 4c..4c+3 (c=t&31) and
// rows r+8*e4 (r=t>>5, e4=0..3) of a 32-row tile. INBUF is an LDS 2D array,
// W is row-major [KDIM][128] in global.
#define GEMM_TILE(INBUF, W, KDIM, ACC)                                         \
    _Pragma("unroll 2")                                                        \
    for (int k0 = 0; k0 < (KDIM); k0 += 4) {                                   \
        const float4 w0 = *(const float4*)((W) + (size_t)(k0 + 0) * HID + 4 * c); \
        const float4 w1 = *(const float4*)((W) + (size_t)(k0 + 1) * HID + 4 * c); \
        const float4 w2 = *(const float4*)((W) + (size_t)(k0 + 2) * HID + 4 * c); \
        const float4 w3 = *(const float4*)((W) + (size_t)(k0 + 3) * HID + 4 * c); \
        _Pragma("unroll")                                                      \
        for (int e4 = 0; e4 < 4; ++e4) {                                       \
            const float4 iv = *(const float4*)(&(INBUF)[r + 8 * e4][k0]);      \
            ACC[e4][0] += iv.x * w0.x + iv.y * w1.x + iv.z * w2.x + iv.w * w3.x; \
            ACC[e4][1] += iv.x * w0.y + iv.y * w1.y + iv.z * w2.y + iv.w * w3.y; \
            ACC[e4][2] += iv.x * w0.z + iv.y * w1.z + iv.z * w2.z + iv.w * w3.z; \
            ACC[e4][3] += iv.x * w0.w + iv.y * w1.w + iv.z * w2.w + iv.w * w3.w; \
        }                                                                      \
    }

__global__ void __launch_bounds__(256, 2)
egc_edge_kernel(const float* __restrict__ x, const float* __restrict__ pos,
                const int* __restrict__ est, const int* __restrict__ eend,
                const float* __restrict__ W1, const float* __restrict__ b1,
                const float* __restrict__ W2, const float* __restrict__ b2,
                const float* __restrict__ fw, const float* __restrict__ fb,
                float* __restrict__ m_i)
{
    __shared__ float in_lds[EB][IN_STRIDE];   // [x_st | x_end] per edge
    __shared__ float m1[EB][MS];
    __shared__ float m2[EB][MS];
    __shared__ float dist_l[EB];
    __shared__ float eval_l[EB];
    __shared__ int   st_l[EB];

    const int t  = threadIdx.x;
    const int e0 = blockIdx.x * EB;
    const int c  = t & 31;
    const int r  = t >> 5;

    // ---- stage: 32 edges x 256 floats, one wave per edge-row (coalesced) ----
    #pragma unroll
    for (int i = 0; i < 8; ++i) {
        int f    = t + 256 * i;          // 0..2047 float4 slots
        int e    = f >> 6;               // local edge
        int slot = f & 63;               // float4 slot within row
        int ge   = e0 + e;
        int node = (slot < 32) ? est[ge] : eend[ge];
        float4 v = *(const float4*)(x + (size_t)node * HID + (size_t)(slot & 31) * 4);
        *(float4*)(&in_lds[e][slot * 4]) = v;
    }
    if (t < EB) {
        int ge = e0 + t;
        int a = est[ge], b = eend[ge];
        st_l[t] = a;
        float dx = pos[a * 3 + 0] - pos[b * 3 + 0];
        float dy = pos[a * 3 + 1] - pos[b * 3 + 1];
        float dz = pos[a * 3 + 2] - pos[b * 3 + 2];
        dx *= dx; dy *= dy; dz *= dz;
        // ||square(d)||_2 per reference
        dist_l[t] = sqrtf(dx * dx + dy * dy + dz * dz);
    }
    __syncthreads();

    // ---- GEMM1: m1 = tanh(in @ W1[0:256] + dist*W1[256] + b1) ----
    {
        float acc[4][4] = {};
        GEMM_TILE(in_lds, W1, 256, acc)
        const float4 wl = *(const float4*)(W1 + (size_t)256 * HID + 4 * c);
        const float4 bb = *(const float4*)(b1 + 4 * c);
        #pragma unroll
        for (int e4 = 0; e4 < 4; ++e4) {
            int e = r + 8 * e4;
            float dd = dist_l[e];
            float4 v;
            v.x = fast_tanh(acc[e4][0] + dd * wl.x + bb.x);
            v.y = fast_tanh(acc[e4][1] + dd * wl.y + bb.y);
            v.z = fast_tanh(acc[e4][2] + dd * wl.z + bb.z);
            v.w = fast_tanh(acc[e4][3] + dd * wl.w + bb.w);
            *(float4*)(&m1[e][4 * c]) = v;
        }
    }
    __syncthreads();

    // ---- GEMM2: m2 = tanh(m1 @ W2 + b2) ----
    {
        float acc[4][4] = {};
        GEMM_TILE(m1, W2, 128, acc)
        const float4 bb = *(const float4*)(b2 + 4 * c);
        #pragma unroll
        for (int e4 = 0; e4 < 4; ++e4) {
            int e = r + 8 * e4;
            float4 v;
            v.x = fast_tanh(acc[e4][0] + bb.x);
            v.y = fast_tanh(acc[e4][1] + bb.y);
            v.z = fast_tanh(acc[e4][2] + bb.z);
            v.w = fast_tanh(acc[e4][3] + bb.w);
            *(float4*)(&m2[e][4 * c]) = v;
        }
    }
    __syncthreads();

    // ---- f_inf gate: e = tanh(m2 @ fw + fb), 4 threads per edge ----
    if (t < 128) {
        int e = t >> 2, p = t & 3;
        float s = 0.0f;
        #pragma unroll
        for (int k = 0; k < 32; ++k) s += m2[e][p * 32 + k] * fw[p * 32 + k];
        s += __shfl_xor(s, 1);
        s += __shfl_xor(s, 2);
        if (p == 0) eval_l[e] = fast_tanh(s + fb[0]);
    }
    __syncthreads();

    // ---- scatter: m_i[st] += e * m2 (fp32 atomics, 8 lanes per edge) ----
    {
        int e = t >> 3, l8 = t & 7;
        float ev = eval_l[e];
        size_t base = (size_t)st_l[e] * HID + l8;
        #pragma unroll
        for (int i = 0; i < 16; ++i) {
            unsafeAtomicAdd(m_i + base + 8 * i, ev * m2[e][l8 + 8 * i]);
        }
    }
}

__global__ void __launch_bounds__(256, 2)
egc_node_kernel(const float* __restrict__ x, const float* __restrict__ m_i,
                const float* __restrict__ hw1, const float* __restrict__ hb1,
                const float* __restrict__ hw2, const float* __restrict__ hb2,
                const float* __restrict__ l1w, const float* __restrict__ l1b,
                const float* __restrict__ l2w, const float* __restrict__ l2b,
                const float* __restrict__ l3w, const float* __restrict__ l3b,
                const float* __restrict__ l4w, const float* __restrict__ l4b,
                const float* __restrict__ l5w, const float* __restrict__ l5b,
                float* __restrict__ out)
{
    __shared__ float in_lds[NB][IN_STRIDE];   // [x | m_i]
    __shared__ float bA[NB][MS];
    __shared__ float bB[NB][MS];

    const int t  = threadIdx.x;
    const int n0 = blockIdx.x * NB;
    const int c  = t & 31;
    const int r  = t >> 5;

    // ---- stage: [x | m_i], one wave per node-row ----
    #pragma unroll
    for (int i = 0; i < 8; ++i) {
        int f    = t + 256 * i;
        int n    = f >> 6;
        int slot = f & 63;
        int node = n0 + n;
        const float* src = (slot < 32) ? (x + (size_t)node * HID)
                                       : (m_i + (size_t)node * HID);
        float4 v = *(const float4*)(src + (size_t)(slot & 31) * 4);
        *(float4*)(&in_lds[n][slot * 4]) = v;
    }
    __syncthreads();

    // ---- t1 = tanh(h @ hw1 + hb1), K=256 ----
    {
        float acc[4][4] = {};
        GEMM_TILE(in_lds, hw1, 256, acc)
        const float4 bb = *(const float4*)(hb1 + 4 * c);
        #pragma unroll
        for (int e4 = 0; e4 < 4; ++e4) {
            int n = r + 8 * e4;
            float4 v;
            v.x = fast_tanh(acc[e4][0] + bb.x);
            v.y = fast_tanh(acc[e4][1] + bb.y);
            v.z = fast_tanh(acc[e4][2] + bb.z);
            v.w = fast_tanh(acc[e4][3] + bb.w);
            *(float4*)(&bA[n][4 * c]) = v;
        }
    }
    __syncthreads();

    // ---- x1 = x + t1 @ hw2 + hb2 (residual, no activation) ----
    {
        float acc[4][4] = {};
        GEMM_TILE(bA, hw2, 128, acc)
        const float4 bb = *(const float4*)(hb2 + 4 * c);
        #pragma unroll
        for (int e4 = 0; e4 < 4; ++e4) {
            int n = r + 8 * e4;
            const float4 rv = *(const float4*)(&in_lds[n][4 * c]);   // x part
            float4 v;
            v.x = acc[e4][0] + bb.x + rv.x;
            v.y = acc[e4][1] + bb.y + rv.y;
            v.z = acc[e4][2] + bb.z + rv.z;
            v.w = acc[e4][3] + bb.w + rv.w;
            *(float4*)(&bB[n][4 * c]) = v;
        }
    }
    __syncthreads();

    // ---- l1..l4: lrelu(v @ W + b), ping-pong bB->bA->bB->bA->bB ----
    const float* Ws[4] = { l1w, l2w, l3w, l4w };
    const float* Bs[4] = { l1b, l2b, l3b, l4b };
    #pragma unroll 1
    for (int layer = 0; layer < 4; ++layer) {
        float acc[4][4] = {};
        if (layer & 1) { GEMM_TILE(bA, Ws[layer], 128, acc) }
        else           { GEMM_TILE(bB, Ws[layer], 128, acc) }
        const float4 bb = *(const float4*)(Bs[layer] + 4 * c);
        __syncthreads();   // done reading src buffer before overwrite? (src != dst, but keep read-before-write of dst safe)
        #pragma unroll
        for (int e4 = 0; e4 < 4; ++e4) {
            int n = r + 8 * e4;
            float4 v;
            v.x = lrelu(acc[e4][0] + bb.x);
            v.y = lrelu(acc[e4][1] + bb.y);
            v.z = lrelu(acc[e4][2] + bb.z);
            v.w = lrelu(acc[e4][3] + bb.w);
            if (layer & 1) *(float4*)(&bB[n][4 * c]) = v;
            else           *(float4*)(&bA[n][4 * c]) = v;
        }
        __syncthreads();
    }
    // after 4 layers the live buffer is bA(l1)->bB(l2)->bA(l3)->bB(l4): final in bB? 
    // layer0 reads bB writes bA; layer1 reads bA writes bB; layer2 reads bB writes bA;
    // layer3 reads bA writes bB  => final activations in bB.

    // ---- l5 head: out[n][3] = bB[n] @ l5w + l5b ----
    if (t < 3 * NB) {
        int n = t / 3, cc = t % 3;
        float s = 0.0f;
        #pragma unroll 4
        for (int k = 0; k < HID; ++k) s += bB[n][k] * l5w[k * 3 + cc];
        out[(size_t)(n0 + n) * 3 + cc] = s + l5b[cc];
    }
}

extern "C" void kernel_launch(void* const* d_in, const int* in_sizes, int n_in,
                              void* d_out, int out_size, void* d_ws, size_t ws_size,
                              hipStream_t stream)
{
    const float* x      = (const float*)d_in[0];
    const float* pos    = (const float*)d_in[1];
    const int*   eidx   = (const int*)d_in[2];
    const float* fe_w1  = (const float*)d_in[3];
    const float* fe_b1  = (const float*)d_in[4];
    const float* fe_w2  = (const float*)d_in[5];
    const float* fe_b2  = (const float*)d_in[6];
    const float* finf_w = (const float*)d_in[7];
    const float* finf_b = (const float*)d_in[8];
    const float* fh_w1  = (const float*)d_in[9];
    const float* fh_b1  = (const float*)d_in[10];
    const float* fh_w2  = (const float*)d_in[11];
    const float* fh_b2  = (const float*)d_in[12];
    const float* l1w    = (const float*)d_in[13];
    const float* l1b    = (const float*)d_in[14];
    const float* l2w    = (const float*)d_in[15];
    const float* l2b    = (const float*)d_in[16];
    const float* l3w    = (const float*)d_in[17];
    const float* l3b    = (const float*)d_in[18];
    const float* l4w    = (const float*)d_in[19];
    const float* l4b    = (const float*)d_in[20];
    const float* l5w    = (const float*)d_in[21];
    const float* l5b    = (const float*)d_in[22];
    float* out = (float*)d_out;
    float* m_i = (float*)d_ws;                       // [n_nodes][128] fp32 accumulator

    const int n_edges = in_sizes[2] / 2;             // 600000
    const int n_nodes = in_sizes[0] / HID;           // 100000

    hipMemsetAsync(m_i, 0, (size_t)n_nodes * HID * sizeof(float), stream);

    // sizes divide exactly: 600000/32=18750, 100000/32=3125
    egc_edge_kernel<<<dim3(n_edges / EB), dim3(256), 0, stream>>>(
        x, pos, eidx, eidx + n_edges, fe_w1, fe_b1, fe_w2, fe_b2, finf_w, finf_b, m_i);

    egc_node_kernel<<<dim3(n_nodes / NB), dim3(256), 0, stream>>>(
        x, m_i, fh_w1, fh_b1, fh_w2, fh_b2, l1w, l1b, l2w, l2b,
        l3w, l3b, l4w, l4b, l5w, l5b, out);
}

// Round 3
// 697.326 us; speedup vs baseline: 2.3919x; 2.3919x over previous
//
#include <hip/hip_runtime.h>
#include <math.h>

#define HID 128

typedef unsigned short u16;
typedef __attribute__((ext_vector_type(8))) short bfrag;      // 8 bf16 (4 VGPRs)
typedef __attribute__((ext_vector_type(4))) float f32x4;      // MFMA C/D
typedef __attribute__((ext_vector_type(8))) unsigned short u16x8;

__device__ __forceinline__ float fast_tanh(float v) {
    v = fminf(15.0f, fmaxf(-15.0f, v));
    float e = __expf(2.0f * v);
    return (e - 1.0f) / (e + 1.0f);
}

// fp32 -> bf16 round-to-nearest-even
__device__ __forceinline__ u16 f2b(float f) {
    union { float f; unsigned int u; } v;
    v.f = f;
    unsigned int u = v.u;
    return (u16)((u + 0x7FFFu + ((u >> 16) & 1u)) >> 16);
}

// ---------------- prep: x -> bf16 ----------------
__global__ void __launch_bounds__(256) prep_x(const float* __restrict__ x,
                                              u16* __restrict__ xb) {
    int i = blockIdx.x * 256 + threadIdx.x;          // 1.6M threads, 8 floats each
    const float4 v0 = *(const float4*)(x + (size_t)i * 8);
    const float4 v1 = *(const float4*)(x + (size_t)i * 8 + 4);
    u16x8 o = { f2b(v0.x), f2b(v0.y), f2b(v0.z), f2b(v0.w),
                f2b(v1.x), f2b(v1.y), f2b(v1.z), f2b(v1.w) };
    *(u16x8*)(xb + (size_t)i * 8) = o;
}

// ---------------- prep: weights -> k-major bf16 ----------------
__global__ void __launch_bounds__(256) prep_weights(
    const float* __restrict__ w1, const float* __restrict__ fh1,
    const float* __restrict__ w2, const float* __restrict__ fh2,
    const float* __restrict__ l1, const float* __restrict__ l2,
    const float* __restrict__ l3, const float* __restrict__ l4,
    u16* __restrict__ w1t, u16* __restrict__ fh1t,
    u16* __restrict__ w2t, u16* __restrict__ fh2t,
    u16* __restrict__ l1t, u16* __restrict__ l2t,
    u16* __restrict__ l3t, u16* __restrict__ l4t)
{
    int b = blockIdx.x, t = threadIdx.x;
    const float* src; u16* dst; int K;
    if (b < 256) {
        K = 256;
        if (b < 128) { src = w1;  dst = w1t; }
        else         { src = fh1; dst = fh1t; b -= 128; }
    } else {
        K = 128;
        int s = (b - 256) >> 6; b = (b - 256) & 63;
        switch (s) {
            case 0:  src = w2;  dst = w2t;  break;
            case 1:  src = fh2; dst = fh2t; break;
            case 2:  src = l1;  dst = l1t;  break;
            case 3:  src = l2;  dst = l2t;  break;
            case 4:  src = l3;  dst = l3t;  break;
            default: src = l4;  dst = l4t;  break;
        }
    }
    int idx = b * 256 + t;            // < K*128
    int k = idx >> 7, n = idx & 127;
    dst[(size_t)n * K + k] = f2b(src[(size_t)k * 128 + n]);
}

// ---------------- shared GEMM tile ----------------
// 32 rows x 128 cols per block; wave w owns cols [32w, 32w+32).
// A from swizzled LDS (row stride = KD*2 bytes, byte ^= (row&7)<<4),
// B from global k-major bf16 (row n -> KD contiguous bf16).
// A and B fragments use the SAME (lane,j)->k map, so k-layout details cancel.
template<int KD>
__device__ __forceinline__ void gemm_k(const u16* sbuf, const u16* __restrict__ wt,
                                       int w, int l16, int l4g, f32x4 (&acc)[2][2]) {
    const int RS = KD * 2;
#pragma unroll
    for (int k0 = 0; k0 < KD; k0 += 32) {
        const int kb = k0 * 2 + l4g * 16;
        bfrag a0 = *(const bfrag*)((const char*)sbuf +
                    (unsigned)((l16 * RS + kb) ^ ((l16 & 7) << 4)));
        bfrag a1 = *(const bfrag*)((const char*)sbuf +
                    (unsigned)(((16 + l16) * RS + kb) ^ ((l16 & 7) << 4)));
        bfrag b0 = *(const bfrag*)((const char*)wt + (size_t)(32 * w + l16) * RS + kb);
        bfrag b1 = *(const bfrag*)((const char*)wt + (size_t)(32 * w + 16 + l16) * RS + kb);
        acc[0][0] = __builtin_amdgcn_mfma_f32_16x16x32_bf16(a0, b0, acc[0][0], 0, 0, 0);
        acc[0][1] = __builtin_amdgcn_mfma_f32_16x16x32_bf16(a0, b1, acc[0][1], 0, 0, 0);
        acc[1][0] = __builtin_amdgcn_mfma_f32_16x16x32_bf16(a1, b0, acc[1][0], 0, 0, 0);
        acc[1][1] = __builtin_amdgcn_mfma_f32_16x16x32_bf16(a1, b1, acc[1][1], 0, 0, 0);
    }
}

// ---------------- edge kernel ----------------
__global__ void __launch_bounds__(256, 3)
egc_edge_mfma(const u16* __restrict__ xb, const float* __restrict__ pos,
              const int* __restrict__ est, const int* __restrict__ eend,
              const u16* __restrict__ w1t, const float* __restrict__ w1last,
              const float* __restrict__ b1, const u16* __restrict__ w2t,
              const float* __restrict__ b2, const float* __restrict__ fw,
              const float* __restrict__ fb, float* __restrict__ m_i)
{
    __shared__ __attribute__((aligned(16))) u16 a_sh[32 * 256];   // [x_st|x_end] bf16, swz
    __shared__ __attribute__((aligned(16))) u16 m1_sh[32 * 128];  // bf16, swz
    __shared__ float m2_sh[32][132];                              // fp32, padded
    __shared__ float dist_l[32];
    __shared__ float ev_l[32];
    __shared__ int   st_l[32];

    const int t = threadIdx.x;
    const int e0 = blockIdx.x * 32;
    const int lane = t & 63;
    const int w = t >> 6;
    const int l16 = lane & 15, l4g = lane >> 4;

    // stage A tile: 32 edges x 512B (x_st 256B | x_end 256B), 16B chunks
#pragma unroll
    for (int i = 0; i < 4; ++i) {
        int f = t + 256 * i;            // 1024 chunks
        int e = f >> 5, q = f & 31;
        int ge = e0 + e;
        int node = (q < 16) ? est[ge] : eend[ge];
        float4 v = *(const float4*)(xb + (size_t)node * 128 + (q & 15) * 8);
        unsigned byte = (unsigned)(e * 512 + q * 16) ^ (unsigned)((e & 7) << 4);
        *(float4*)((char*)a_sh + byte) = v;
    }
    if (t < 32) {
        int ge = e0 + t;
        int a = est[ge], b = eend[ge];
        st_l[t] = a;
        float dx = pos[a * 3 + 0] - pos[b * 3 + 0];
        float dy = pos[a * 3 + 1] - pos[b * 3 + 1];
        float dz = pos[a * 3 + 2] - pos[b * 3 + 2];
        dx *= dx; dy *= dy; dz *= dz;
        dist_l[t] = sqrtf(dx * dx + dy * dy + dz * dz);   // ||square(d)||_2
    }
    __syncthreads();

    // GEMM1: K=256, + dist * w1[256] + b1, tanh -> m1 (bf16 LDS)
    {
        f32x4 acc[2][2] = {};
        gemm_k<256>(a_sh, w1t, w, l16, l4g, acc);
#pragma unroll
        for (int mi = 0; mi < 2; ++mi)
#pragma unroll
            for (int ni = 0; ni < 2; ++ni) {
                const int col = 32 * w + 16 * ni + l16;
                const float wl = w1last[col], bb = b1[col];
#pragma unroll
                for (int rg = 0; rg < 4; ++rg) {
                    const int row = 16 * mi + l4g * 4 + rg;
                    float v = fast_tanh(acc[mi][ni][rg] + dist_l[row] * wl + bb);
                    unsigned byte = (unsigned)((row * 256 + col * 2) ^ ((row & 7) << 4));
                    *(u16*)((char*)m1_sh + byte) = f2b(v);
                }
            }
    }
    __syncthreads();

    // GEMM2: K=128, tanh -> m2 (fp32 LDS)
    {
        f32x4 acc[2][2] = {};
        gemm_k<128>(m1_sh, w2t, w, l16, l4g, acc);
#pragma unroll
        for (int mi = 0; mi < 2; ++mi)
#pragma unroll
            for (int ni = 0; ni < 2; ++ni) {
                const int col = 32 * w + 16 * ni + l16;
                const float bb = b2[col];
#pragma unroll
                for (int rg = 0; rg < 4; ++rg) {
                    const int row = 16 * mi + l4g * 4 + rg;
                    m2_sh[row][col] = fast_tanh(acc[mi][ni][rg] + bb);
                }
            }
    }
    __syncthreads();

    // gate: e = tanh(m2 . fw + fb), 4 threads/edge
    if (t < 128) {
        int e = t >> 2, p = t & 3;
        float s = 0.0f;
#pragma unroll
        for (int k = 0; k < 32; ++k) s += m2_sh[e][p * 32 + k] * fw[p * 32 + k];
        s += __shfl_xor(s, 1);
        s += __shfl_xor(s, 2);
        if (p == 0) ev_l[e] = fast_tanh(s + fb[0]);
    }
    __syncthreads();

    // scatter: m_i[st] += e * m2
    {
        int e = t >> 3, l8 = t & 7;
        float ev = ev_l[e];
        size_t base = (size_t)st_l[e] * HID + l8;
#pragma unroll
        for (int i = 0; i < 16; ++i)
            unsafeAtomicAdd(m_i + base + 8 * i, ev * m2_sh[e][l8 + 8 * i]);
    }
}

// ---------------- node kernel ----------------
// GEMM + epilogue macro over named LDS buffers (no LDS pointer arrays:
// addrspace(3) pointer arrays fail to compile).
#define NODE_LAYER(SRC, KD, WT, BIAS, EPILOG)                                  \
    {                                                                          \
        f32x4 acc[2][2] = {};                                                  \
        gemm_k<KD>(SRC, WT, w, l16, l4g, acc);                                 \
        _Pragma("unroll")                                                      \
        for (int mi = 0; mi < 2; ++mi)                                         \
            _Pragma("unroll")                                                  \
            for (int ni = 0; ni < 2; ++ni) {                                   \
                const int col = 32 * w + 16 * ni + l16;                        \
                const float bb = (BIAS)[col];                                  \
                _Pragma("unroll")                                              \
                for (int rg = 0; rg < 4; ++rg) {                               \
                    const int row = 16 * mi + l4g * 4 + rg;                    \
                    float v = acc[mi][ni][rg] + bb;                            \
                    EPILOG;                                                    \
                }                                                              \
            }                                                                  \
    }

#define STORE_BF16(DST) do {                                                   \
        unsigned byte = (unsigned)((row * 256 + col * 2) ^ ((row & 7) << 4));  \
        *(u16*)((char*)(DST) + byte) = f2b(v);                                 \
    } while (0)

__global__ void __launch_bounds__(256, 3)
egc_node_mfma(const u16* __restrict__ xb, const float* __restrict__ xf,
              const float* __restrict__ m_i,
              const u16* __restrict__ fh1t, const float* __restrict__ hb1,
              const u16* __restrict__ fh2t, const float* __restrict__ hb2,
              const u16* __restrict__ l1t, const float* __restrict__ l1b,
              const u16* __restrict__ l2t, const float* __restrict__ l2b,
              const u16* __restrict__ l3t, const float* __restrict__ l3b,
              const u16* __restrict__ l4t, const float* __restrict__ l4b,
              const float* __restrict__ l5w, const float* __restrict__ l5b,
              float* __restrict__ out)
{
    __shared__ __attribute__((aligned(16))) u16 a_sh[32 * 256];   // [x|m_i] bf16, swz
    __shared__ __attribute__((aligned(16))) u16 bA[32 * 128];
    __shared__ __attribute__((aligned(16))) u16 bB[32 * 128];
    __shared__ float ff[32][132];                                 // l4 out, fp32

    const int t = threadIdx.x;
    const int n0 = blockIdx.x * 32;
    const int lane = t & 63;
    const int w = t >> 6;
    const int l16 = lane & 15, l4g = lane >> 4;

    // stage x (bf16 direct)
#pragma unroll
    for (int i = 0; i < 2; ++i) {
        int f = t + 256 * i;            // 512 chunks
        int n = f >> 4, q = f & 15;
        float4 v = *(const float4*)(xb + (size_t)(n0 + n) * 128 + q * 8);
        unsigned byte = (unsigned)((n * 512 + q * 16) ^ ((n & 7) << 4));
        *(float4*)((char*)a_sh + byte) = v;
    }
    // stage m_i (fp32 -> bf16)
#pragma unroll
    for (int i = 0; i < 2; ++i) {
        int f = t + 256 * i;
        int n = f >> 4, q = f & 15;
        const float* src = m_i + (size_t)(n0 + n) * 128 + q * 8;
        float4 v0 = *(const float4*)(src);
        float4 v1 = *(const float4*)(src + 4);
        u16x8 o = { f2b(v0.x), f2b(v0.y), f2b(v0.z), f2b(v0.w),
                    f2b(v1.x), f2b(v1.y), f2b(v1.z), f2b(v1.w) };
        unsigned byte = (unsigned)((n * 512 + 256 + q * 16) ^ ((n & 7) << 4));
        *(u16x8*)((char*)a_sh + byte) = o;
    }
    __syncthreads();

    // fh1: K=256, tanh -> bA
    NODE_LAYER(a_sh, 256, fh1t, hb1, { v = fast_tanh(v); STORE_BF16(bA); })
    __syncthreads();

    // fh2: K=128, + hb2 + x residual (fp32 from global) -> bB
    NODE_LAYER(bA, 128, fh2t, hb2,
               { v += xf[(size_t)(n0 + row) * HID + col]; STORE_BF16(bB); })
    __syncthreads();

    // l1: bB -> bA
    NODE_LAYER(bB, 128, l1t, l1b, { v = v > 0.0f ? v : 0.01f * v; STORE_BF16(bA); })
    __syncthreads();
    // l2: bA -> bB
    NODE_LAYER(bA, 128, l2t, l2b, { v = v > 0.0f ? v : 0.01f * v; STORE_BF16(bB); })
    __syncthreads();
    // l3: bB -> bA
    NODE_LAYER(bB, 128, l3t, l3b, { v = v > 0.0f ? v : 0.01f * v; STORE_BF16(bA); })
    __syncthreads();
    // l4: bA -> ff (fp32)
    NODE_LAYER(bA, 128, l4t, l4b,
               { ff[row][col] = v > 0.0f ? v : 0.01f * v; })
    __syncthreads();

    // l5 head
    if (t < 96) {
        int n = t / 3, cc = t % 3;
        float s = l5b[cc];
#pragma unroll 8
        for (int k = 0; k < HID; ++k) s += ff[n][k] * l5w[k * 3 + cc];
        out[(size_t)(n0 + n) * 3 + cc] = s;
    }
}

extern "C" void kernel_launch(void* const* d_in, const int* in_sizes, int n_in,
                              void* d_out, int out_size, void* d_ws, size_t ws_size,
                              hipStream_t stream)
{
    const float* x      = (const float*)d_in[0];
    const float* pos    = (const float*)d_in[1];
    const int*   eidx   = (const int*)d_in[2];
    const float* fe_w1  = (const float*)d_in[3];
    const float* fe_b1  = (const float*)d_in[4];
    const float* fe_w2  = (const float*)d_in[5];
    const float* fe_b2  = (const float*)d_in[6];
    const float* finf_w = (const float*)d_in[7];
    const float* finf_b = (const float*)d_in[8];
    const float* fh_w1  = (const float*)d_in[9];
    const float* fh_b1  = (const float*)d_in[10];
    const float* fh_w2  = (const float*)d_in[11];
    const float* fh_b2  = (const float*)d_in[12];
    const float* l1w    = (const float*)d_in[13];
    const float* l1b    = (const float*)d_in[14];
    const float* l2w    = (const float*)d_in[15];
    const float* l2b    = (const float*)d_in[16];
    const float* l3w    = (const float*)d_in[17];
    const float* l3b    = (const float*)d_in[18];
    const float* l4w    = (const float*)d_in[19];
    const float* l4b    = (const float*)d_in[20];
    const float* l5w    = (const float*)d_in[21];
    const float* l5b    = (const float*)d_in[22];
    float* out = (float*)d_out;

    const int n_edges = in_sizes[2] / 2;             // 600000
    const int n_nodes = in_sizes[0] / HID;           // 100000

    char* ws = (char*)d_ws;
    float* m_i  = (float*)(ws + 0);                  // 51,200,000 B
    u16* xb     = (u16*)(ws + 51200000);             // 25,600,000 B
    u16* w1t    = (u16*)(ws + 76800000);             // 65,536 B (k-major 128x256)
    u16* w2t    = (u16*)(ws + 76865536);             // 32,768 B
    u16* fh1t   = (u16*)(ws + 76898304);             // 65,536 B
    u16* fh2t   = (u16*)(ws + 76963840);             // 32,768 B
    u16* l1t    = (u16*)(ws + 76996608);
    u16* l2t    = (u16*)(ws + 77029376);
    u16* l3t    = (u16*)(ws + 77062144);
    u16* l4t    = (u16*)(ws + 77094912);

    (void)hipMemsetAsync(m_i, 0, (size_t)n_nodes * HID * sizeof(float), stream);
    prep_x<<<dim3((n_nodes * HID) / (256 * 8)), dim3(256), 0, stream>>>(x, xb);
    prep_weights<<<dim3(640), dim3(256), 0, stream>>>(
        fe_w1, fh_w1, fe_w2, fh_w2, l1w, l2w, l3w, l4w,
        w1t, fh1t, w2t, fh2t, l1t, l2t, l3t, l4t);

    egc_edge_mfma<<<dim3(n_edges / 32), dim3(256), 0, stream>>>(
        xb, pos, eidx, eidx + n_edges, w1t, fe_w1 + (size_t)256 * HID, fe_b1,
        w2t, fe_b2, finf_w, finf_b, m_i);

    egc_node_mfma<<<dim3(n_nodes / 32), dim3(256), 0, stream>>>(
        xb, x, m_i, fh1t, fh_b1, fh2t, fh_b2, l1t, l1b, l2t, l2b,
        l3t, l3b, l4t, l4b, l5w, l5b, out);
}

// Round 4
// 524.728 us; speedup vs baseline: 3.1787x; 1.3289x over previous
//
#include <hip/hip_runtime.h>
#include <math.h>

#define HID 128

typedef unsigned short u16;
typedef __attribute__((ext_vector_type(8))) short bfrag;      // 8 bf16 (4 VGPRs)
typedef __attribute__((ext_vector_type(4))) float f32x4;      // MFMA C/D
typedef __attribute__((ext_vector_type(8))) unsigned short u16x8;

__device__ __forceinline__ float fast_tanh(float v) {
    v = fminf(15.0f, fmaxf(-15.0f, v));
    float e = __expf(2.0f * v);
    return (e - 1.0f) / (e + 1.0f);
}

// fp32 -> bf16 round-to-nearest-even
__device__ __forceinline__ u16 f2b(float f) {
    union { float f; unsigned int u; } v;
    v.f = f;
    unsigned int u = v.u;
    return (u16)((u + 0x7FFFu + ((u >> 16) & 1u)) >> 16);
}
__device__ __forceinline__ float b2f(u16 b) {
    union { unsigned int u; float f; } v;
    v.u = ((unsigned int)b) << 16;
    return v.f;
}

// ---------------- prep: x -> bf16 ----------------
__global__ void __launch_bounds__(256) prep_x(const float* __restrict__ x,
                                              u16* __restrict__ xb) {
    int i = blockIdx.x * 256 + threadIdx.x;
    const float4 v0 = *(const float4*)(x + (size_t)i * 8);
    const float4 v1 = *(const float4*)(x + (size_t)i * 8 + 4);
    u16x8 o = { f2b(v0.x), f2b(v0.y), f2b(v0.z), f2b(v0.w),
                f2b(v1.x), f2b(v1.y), f2b(v1.z), f2b(v1.w) };
    *(u16x8*)(xb + (size_t)i * 8) = o;
}

// ---------------- prep: weights -> k-major bf16 ----------------
__global__ void __launch_bounds__(256) prep_weights(
    const float* __restrict__ w1, const float* __restrict__ fh1,
    const float* __restrict__ w2, const float* __restrict__ fh2,
    const float* __restrict__ l1, const float* __restrict__ l2,
    const float* __restrict__ l3, const float* __restrict__ l4,
    u16* __restrict__ w1t, u16* __restrict__ fh1t,
    u16* __restrict__ w2t, u16* __restrict__ fh2t,
    u16* __restrict__ l1t, u16* __restrict__ l2t,
    u16* __restrict__ l3t, u16* __restrict__ l4t)
{
    int b = blockIdx.x, t = threadIdx.x;
    const float* src; u16* dst; int K;
    if (b < 256) {
        K = 256;
        if (b < 128) { src = w1;  dst = w1t; }
        else         { src = fh1; dst = fh1t; b -= 128; }
    } else {
        K = 128;
        int s = (b - 256) >> 6; b = (b - 256) & 63;
        switch (s) {
            case 0:  src = w2;  dst = w2t;  break;
            case 1:  src = fh2; dst = fh2t; break;
            case 2:  src = l1;  dst = l1t;  break;
            case 3:  src = l2;  dst = l2t;  break;
            case 4:  src = l3;  dst = l3t;  break;
            default: src = l4;  dst = l4t;  break;
        }
    }
    int idx = b * 256 + t;
    int k = idx >> 7, n = idx & 127;
    dst[(size_t)n * K + k] = f2b(src[(size_t)k * 128 + n]);
}

// ---------------- CSR build: hist / scan / reorder ----------------
__global__ void __launch_bounds__(256) hist_kernel(const int* __restrict__ est,
                                                   int* __restrict__ cnt, int E) {
    int e = blockIdx.x * 256 + threadIdx.x;
    if (e < E) atomicAdd(&cnt[est[e]], 1);
}

__global__ void __launch_bounds__(256) scan1(const int* __restrict__ cnt,
                                             int* __restrict__ scanout,
                                             int* __restrict__ partial, int N) {
    __shared__ int s[256];
    int t = threadIdx.x, b = blockIdx.x, i = b * 256 + t;
    int v = (i < N) ? cnt[i] : 0;
    s[t] = v; __syncthreads();
#pragma unroll
    for (int d = 1; d < 256; d <<= 1) {
        int add = (t >= d) ? s[t - d] : 0;
        __syncthreads();
        s[t] += add;
        __syncthreads();
    }
    if (i < N) scanout[i] = s[t] - v;          // exclusive within block
    if (t == 255) partial[b] = s[255];
}

__global__ void __launch_bounds__(512) scan2(int* __restrict__ partial, int NB) {
    __shared__ int s[512];
    int t = threadIdx.x;
    int v = (t < NB) ? partial[t] : 0;
    s[t] = v; __syncthreads();
#pragma unroll
    for (int d = 1; d < 512; d <<= 1) {
        int add = (t >= d) ? s[t - d] : 0;
        __syncthreads();
        s[t] += add;
        __syncthreads();
    }
    if (t < NB) partial[t] = s[t] - v;         // exclusive, in place
}

__global__ void __launch_bounds__(256) scan3(const int* __restrict__ scanout,
                                             const int* __restrict__ partial,
                                             int* __restrict__ offs,
                                             int* __restrict__ cur, int N, int E) {
    int t = threadIdx.x, b = blockIdx.x, i = b * 256 + t;
    if (i < N) { int o = scanout[i] + partial[b]; offs[i] = o; cur[i] = o; }
    if (i == 0) offs[N] = E;
}

__global__ void __launch_bounds__(256) reorder_kernel(const int* __restrict__ est,
                                                      int* __restrict__ cur,
                                                      int* __restrict__ perm, int E) {
    int e = blockIdx.x * 256 + threadIdx.x;
    if (e < E) { int p = atomicAdd(&cur[est[e]], 1); perm[p] = e; }
}

// ---------------- shared GEMM tile ----------------
// 32 rows x 128 cols per block; wave w owns cols [32w, 32w+32).
// A from swizzled LDS (row stride = KD*2 bytes, byte ^= (row&7)<<4),
// B from global k-major bf16. A and B use the SAME (lane,j)->k map.
template<int KD>
__device__ __forceinline__ void gemm_k(const u16* sbuf, const u16* __restrict__ wt,
                                       int w, int l16, int l4g, f32x4 (&acc)[2][2]) {
    const int RS = KD * 2;
#pragma unroll
    for (int k0 = 0; k0 < KD; k0 += 32) {
        const int kb = k0 * 2 + l4g * 16;
        bfrag a0 = *(const bfrag*)((const char*)sbuf +
                    (unsigned)((l16 * RS + kb) ^ ((l16 & 7) << 4)));
        bfrag a1 = *(const bfrag*)((const char*)sbuf +
                    (unsigned)(((16 + l16) * RS + kb) ^ ((l16 & 7) << 4)));
        bfrag b0 = *(const bfrag*)((const char*)wt + (size_t)(32 * w + l16) * RS + kb);
        bfrag b1 = *(const bfrag*)((const char*)wt + (size_t)(32 * w + 16 + l16) * RS + kb);
        acc[0][0] = __builtin_amdgcn_mfma_f32_16x16x32_bf16(a0, b0, acc[0][0], 0, 0, 0);
        acc[0][1] = __builtin_amdgcn_mfma_f32_16x16x32_bf16(a0, b1, acc[0][1], 0, 0, 0);
        acc[1][0] = __builtin_amdgcn_mfma_f32_16x16x32_bf16(a1, b0, acc[1][0], 0, 0, 0);
        acc[1][1] = __builtin_amdgcn_mfma_f32_16x16x32_bf16(a1, b1, acc[1][1], 0, 0, 0);
    }
}

// ---------------- edge kernel, CSR path: writes g[e] = e_ij * m_ij (bf16) ----------------
__global__ void __launch_bounds__(256, 4)
egc_edge_csr(const u16* __restrict__ xb, const float* __restrict__ pos,
             const int* __restrict__ est, const int* __restrict__ eend,
             const u16* __restrict__ w1t, const float* __restrict__ w1last,
             const float* __restrict__ b1, const u16* __restrict__ w2t,
             const float* __restrict__ b2, const float* __restrict__ fw,
             const float* __restrict__ fb, u16* __restrict__ g)
{
    __shared__ __attribute__((aligned(16))) u16 a_sh[32 * 256];   // 16 KB, swz
    __shared__ __attribute__((aligned(16))) u16 m1_sh[32 * 128];  // 8 KB, swz
    __shared__ __attribute__((aligned(16))) u16 m2_sh[32][136];   // 8.5 KB, linear
    __shared__ float dist_l[32];
    __shared__ float ev_l[32];

    const int t = threadIdx.x;
    const int e0 = blockIdx.x * 32;
    const int lane = t & 63;
    const int w = t >> 6;
    const int l16 = lane & 15, l4g = lane >> 4;

    // stage A tile: 32 edges x 512B (x_st | x_end), 16B chunks
#pragma unroll
    for (int i = 0; i < 4; ++i) {
        int f = t + 256 * i;
        int e = f >> 5, q = f & 31;
        int ge = e0 + e;
        int node = (q < 16) ? est[ge] : eend[ge];
        float4 v = *(const float4*)(xb + (size_t)node * 128 + (q & 15) * 8);
        unsigned byte = (unsigned)(e * 512 + q * 16) ^ (unsigned)((e & 7) << 4);
        *(float4*)((char*)a_sh + byte) = v;
    }
    if (t < 32) {
        int ge = e0 + t;
        int a = est[ge], b = eend[ge];
        float dx = pos[a * 3 + 0] - pos[b * 3 + 0];
        float dy = pos[a * 3 + 1] - pos[b * 3 + 1];
        float dz = pos[a * 3 + 2] - pos[b * 3 + 2];
        dx *= dx; dy *= dy; dz *= dz;
        dist_l[t] = sqrtf(dx * dx + dy * dy + dz * dz);   // ||square(d)||_2
    }
    __syncthreads();

    // GEMM1: K=256, + dist * w1[256] + b1, tanh -> m1 (bf16 swz LDS)
    {
        f32x4 acc[2][2] = {};
        gemm_k<256>(a_sh, w1t, w, l16, l4g, acc);
#pragma unroll
        for (int mi = 0; mi < 2; ++mi)
#pragma unroll
            for (int ni = 0; ni < 2; ++ni) {
                const int col = 32 * w + 16 * ni + l16;
                const float wl = w1last[col], bb = b1[col];
#pragma unroll
                for (int rg = 0; rg < 4; ++rg) {
                    const int row = 16 * mi + l4g * 4 + rg;
                    float v = fast_tanh(acc[mi][ni][rg] + dist_l[row] * wl + bb);
                    unsigned byte = (unsigned)((row * 256 + col * 2) ^ ((row & 7) << 4));
                    *(u16*)((char*)m1_sh + byte) = f2b(v);
                }
            }
    }
    __syncthreads();

    // GEMM2: K=128, tanh -> m2 (bf16 linear LDS)
    {
        f32x4 acc[2][2] = {};
        gemm_k<128>(m1_sh, w2t, w, l16, l4g, acc);
#pragma unroll
        for (int mi = 0; mi < 2; ++mi)
#pragma unroll
            for (int ni = 0; ni < 2; ++ni) {
                const int col = 32 * w + 16 * ni + l16;
                const float bb = b2[col];
#pragma unroll
                for (int rg = 0; rg < 4; ++rg) {
                    const int row = 16 * mi + l4g * 4 + rg;
                    m2_sh[row][col] = f2b(fast_tanh(acc[mi][ni][rg] + bb));
                }
            }
    }
    __syncthreads();

    // gate: e = tanh(m2 . fw + fb), 4 threads/edge
    if (t < 128) {
        int e = t >> 2, p = t & 3;
        float s = 0.0f;
#pragma unroll
        for (int kk = 0; kk < 4; ++kk) {
            u16x8 mv = *(const u16x8*)&m2_sh[e][p * 32 + kk * 8];
#pragma unroll
            for (int q = 0; q < 8; ++q)
                s += b2f(mv[q]) * fw[p * 32 + kk * 8 + q];
        }
        s += __shfl_xor(s, 1);
        s += __shfl_xor(s, 2);
        if (p == 0) ev_l[e] = fast_tanh(s + fb[0]);
    }
    __syncthreads();

    // store: g[e0+row] = ev * m2[row]  (coalesced, 32B per thread)
    {
        int row = t >> 3, l8 = t & 7;
        float ev = ev_l[row];
        const u16* src = &m2_sh[row][16 * l8];
        u16x8 a = *(const u16x8*)src;
        u16x8 b = *(const u16x8*)(src + 8);
        u16x8 o0, o1;
#pragma unroll
        for (int q = 0; q < 8; ++q) {
            o0[q] = f2b(b2f(a[q]) * ev);
            o1[q] = f2b(b2f(b[q]) * ev);
        }
        u16* dst = g + (size_t)(e0 + row) * 128 + 16 * l8;
        *(u16x8*)dst = o0;
        *(u16x8*)(dst + 8) = o1;
    }
}

// ---------------- gather: m_i[n] = sum over CSR segment of g rows (bf16 out) ----------------
__global__ void __launch_bounds__(256, 8)
gather_kernel(const u16* __restrict__ g, const int* __restrict__ perm,
              const int* __restrict__ offs, u16* __restrict__ m_i)
{
    const int lane = threadIdx.x & 63;
    const int n = blockIdx.x * 4 + (threadIdx.x >> 6);
    const int beg = offs[n], end = offs[n + 1];
    float a0 = 0.0f, a1 = 0.0f;
    for (int base = beg; base < end; base += 64) {
        int m = end - base; if (m > 64) m = 64;
        int idx = (lane < m) ? perm[base + lane] : 0;
        for (int j = 0; j < m; ++j) {
            int e = __shfl(idx, j);
            unsigned v = *(const unsigned*)(g + (size_t)e * 128 + lane * 2);
            union { unsigned u; float f; } lo, hi;
            lo.u = v << 16;
            hi.u = v & 0xFFFF0000u;
            a0 += lo.f;
            a1 += hi.f;
        }
    }
    unsigned o = (unsigned)f2b(a0) | ((unsigned)f2b(a1) << 16);
    ((unsigned*)m_i)[(size_t)n * 64 + lane] = o;
}

// ---------------- edge kernel, fallback atomic path (round-3, proven) ----------------
__global__ void __launch_bounds__(256, 3)
egc_edge_mfma(const u16* __restrict__ xb, const float* __restrict__ pos,
              const int* __restrict__ est, const int* __restrict__ eend,
              const u16* __restrict__ w1t, const float* __restrict__ w1last,
              const float* __restrict__ b1, const u16* __restrict__ w2t,
              const float* __restrict__ b2, const float* __restrict__ fw,
              const float* __restrict__ fb, float* __restrict__ m_i)
{
    __shared__ __attribute__((aligned(16))) u16 a_sh[32 * 256];
    __shared__ __attribute__((aligned(16))) u16 m1_sh[32 * 128];
    __shared__ float m2_sh[32][132];
    __shared__ float dist_l[32];
    __shared__ float ev_l[32];
    __shared__ int   st_l[32];

    const int t = threadIdx.x;
    const int e0 = blockIdx.x * 32;
    const int lane = t & 63;
    const int w = t >> 6;
    const int l16 = lane & 15, l4g = lane >> 4;

#pragma unroll
    for (int i = 0; i < 4; ++i) {
        int f = t + 256 * i;
        int e = f >> 5, q = f & 31;
        int ge = e0 + e;
        int node = (q < 16) ? est[ge] : eend[ge];
        float4 v = *(const float4*)(xb + (size_t)node * 128 + (q & 15) * 8);
        unsigned byte = (unsigned)(e * 512 + q * 16) ^ (unsigned)((e & 7) << 4);
        *(float4*)((char*)a_sh + byte) = v;
    }
    if (t < 32) {
        int ge = e0 + t;
        int a = est[ge], b = eend[ge];
        st_l[t] = a;
        float dx = pos[a * 3 + 0] - pos[b * 3 + 0];
        float dy = pos[a * 3 + 1] - pos[b * 3 + 1];
        float dz = pos[a * 3 + 2] - pos[b * 3 + 2];
        dx *= dx; dy *= dy; dz *= dz;
        dist_l[t] = sqrtf(dx * dx + dy * dy + dz * dz);
    }
    __syncthreads();

    {
        f32x4 acc[2][2] = {};
        gemm_k<256>(a_sh, w1t, w, l16, l4g, acc);
#pragma unroll
        for (int mi = 0; mi < 2; ++mi)
#pragma unroll
            for (int ni = 0; ni < 2; ++ni) {
                const int col = 32 * w + 16 * ni + l16;
                const float wl = w1last[col], bb = b1[col];
#pragma unroll
                for (int rg = 0; rg < 4; ++rg) {
                    const int row = 16 * mi + l4g * 4 + rg;
                    float v = fast_tanh(acc[mi][ni][rg] + dist_l[row] * wl + bb);
                    unsigned byte = (unsigned)((row * 256 + col * 2) ^ ((row & 7) << 4));
                    *(u16*)((char*)m1_sh + byte) = f2b(v);
                }
            }
    }
    __syncthreads();

    {
        f32x4 acc[2][2] = {};
        gemm_k<128>(m1_sh, w2t, w, l16, l4g, acc);
#pragma unroll
        for (int mi = 0; mi < 2; ++mi)
#pragma unroll
            for (int ni = 0; ni < 2; ++ni) {
                const int col = 32 * w + 16 * ni + l16;
                const float bb = b2[col];
#pragma unroll
                for (int rg = 0; rg < 4; ++rg) {
                    const int row = 16 * mi + l4g * 4 + rg;
                    m2_sh[row][col] = fast_tanh(acc[mi][ni][rg] + bb);
                }
            }
    }
    __syncthreads();

    if (t < 128) {
        int e = t >> 2, p = t & 3;
        float s = 0.0f;
#pragma unroll
        for (int k = 0; k < 32; ++k) s += m2_sh[e][p * 32 + k] * fw[p * 32 + k];
        s += __shfl_xor(s, 1);
        s += __shfl_xor(s, 2);
        if (p == 0) ev_l[e] = fast_tanh(s + fb[0]);
    }
    __syncthreads();

    {
        int e = t >> 3, l8 = t & 7;
        float ev = ev_l[e];
        size_t base = (size_t)st_l[e] * HID + l8;
#pragma unroll
        for (int i = 0; i < 16; ++i)
            unsafeAtomicAdd(m_i + base + 8 * i, ev * m2_sh[e][l8 + 8 * i]);
    }
}

// ---------------- node kernel ----------------
#define NODE_LAYER(SRC, KD, WT, BIAS, EPILOG)                                  \
    {                                                                          \
        f32x4 acc[2][2] = {};                                                  \
        gemm_k<KD>(SRC, WT, w, l16, l4g, acc);                                 \
        _Pragma("unroll")                                                      \
        for (int mi = 0; mi < 2; ++mi)                                         \
            _Pragma("unroll")                                                  \
            for (int ni = 0; ni < 2; ++ni) {                                   \
                const int col = 32 * w + 16 * ni + l16;                        \
                const float bb = (BIAS)[col];                                  \
                _Pragma("unroll")                                              \
                for (int rg = 0; rg < 4; ++rg) {                               \
                    const int row = 16 * mi + l4g * 4 + rg;                    \
                    float v = acc[mi][ni][rg] + bb;                            \
                    EPILOG;                                                    \
                }                                                              \
            }                                                                  \
    }

#define STORE_BF16(DST) do {                                                   \
        unsigned byte = (unsigned)((row * 256 + col * 2) ^ ((row & 7) << 4));  \
        *(u16*)((char*)(DST) + byte) = f2b(v);                                 \
    } while (0)

template<bool MIBF16>
__global__ void __launch_bounds__(256, 3)
egc_node_mfma(const u16* __restrict__ xb, const float* __restrict__ xf,
              const void* __restrict__ m_i,
              const u16* __restrict__ fh1t, const float* __restrict__ hb1,
              const u16* __restrict__ fh2t, const float* __restrict__ hb2,
              const u16* __restrict__ l1t, const float* __restrict__ l1b,
              const u16* __restrict__ l2t, const float* __restrict__ l2b,
              const u16* __restrict__ l3t, const float* __restrict__ l3b,
              const u16* __restrict__ l4t, const float* __restrict__ l4b,
              const float* __restrict__ l5w, const float* __restrict__ l5b,
              float* __restrict__ out)
{
    __shared__ __attribute__((aligned(16))) u16 a_sh[32 * 256];   // [x|m_i] bf16, swz
    __shared__ __attribute__((aligned(16))) u16 bA[32 * 128];
    __shared__ __attribute__((aligned(16))) u16 bB[32 * 128];
    __shared__ float ff[32][132];

    const int t = threadIdx.x;
    const int n0 = blockIdx.x * 32;
    const int lane = t & 63;
    const int w = t >> 6;
    const int l16 = lane & 15, l4g = lane >> 4;

    // stage x (bf16 direct)
#pragma unroll
    for (int i = 0; i < 2; ++i) {
        int f = t + 256 * i;
        int n = f >> 4, q = f & 15;
        float4 v = *(const float4*)(xb + (size_t)(n0 + n) * 128 + q * 8);
        unsigned byte = (unsigned)((n * 512 + q * 16) ^ ((n & 7) << 4));
        *(float4*)((char*)a_sh + byte) = v;
    }
    // stage m_i
    if (MIBF16) {
#pragma unroll
        for (int i = 0; i < 2; ++i) {
            int f = t + 256 * i;
            int n = f >> 4, q = f & 15;
            float4 v = *(const float4*)((const u16*)m_i + (size_t)(n0 + n) * 128 + q * 8);
            unsigned byte = (unsigned)((n * 512 + 256 + q * 16) ^ ((n & 7) << 4));
            *(float4*)((char*)a_sh + byte) = v;
        }
    } else {
#pragma unroll
        for (int i = 0; i < 2; ++i) {
            int f = t + 256 * i;
            int n = f >> 4, q = f & 15;
            const float* src = (const float*)m_i + (size_t)(n0 + n) * 128 + q * 8;
            float4 v0 = *(const float4*)(src);
            float4 v1 = *(const float4*)(src + 4);
            u16x8 o = { f2b(v0.x), f2b(v0.y), f2b(v0.z), f2b(v0.w),
                        f2b(v1.x), f2b(v1.y), f2b(v1.z), f2b(v1.w) };
            unsigned byte = (unsigned)((n * 512 + 256 + q * 16) ^ ((n & 7) << 4));
            *(u16x8*)((char*)a_sh + byte) = o;
        }
    }
    __syncthreads();

    NODE_LAYER(a_sh, 256, fh1t, hb1, { v = fast_tanh(v); STORE_BF16(bA); })
    __syncthreads();
    NODE_LAYER(bA, 128, fh2t, hb2,
               { v += xf[(size_t)(n0 + row) * HID + col]; STORE_BF16(bB); })
    __syncthreads();
    NODE_LAYER(bB, 128, l1t, l1b, { v = v > 0.0f ? v : 0.01f * v; STORE_BF16(bA); })
    __syncthreads();
    NODE_LAYER(bA, 128, l2t, l2b, { v = v > 0.0f ? v : 0.01f * v; STORE_BF16(bB); })
    __syncthreads();
    NODE_LAYER(bB, 128, l3t, l3b, { v = v > 0.0f ? v : 0.01f * v; STORE_BF16(bA); })
    __syncthreads();
    NODE_LAYER(bA, 128, l4t, l4b, { ff[row][col] = v > 0.0f ? v : 0.01f * v; })
    __syncthreads();

    if (t < 96) {
        int n = t / 3, cc = t % 3;
        float s = l5b[cc];
#pragma unroll 8
        for (int k = 0; k < HID; ++k) s += ff[n][k] * l5w[k * 3 + cc];
        out[(size_t)(n0 + n) * 3 + cc] = s;
    }
}

extern "C" void kernel_launch(void* const* d_in, const int* in_sizes, int n_in,
                              void* d_out, int out_size, void* d_ws, size_t ws_size,
                              hipStream_t stream)
{
    const float* x      = (const float*)d_in[0];
    const float* pos    = (const float*)d_in[1];
    const int*   eidx   = (const int*)d_in[2];
    const float* fe_w1  = (const float*)d_in[3];
    const float* fe_b1  = (const float*)d_in[4];
    const float* fe_w2  = (const float*)d_in[5];
    const float* fe_b2  = (const float*)d_in[6];
    const float* finf_w = (const float*)d_in[7];
    const float* finf_b = (const float*)d_in[8];
    const float* fh_w1  = (const float*)d_in[9];
    const float* fh_b1  = (const float*)d_in[10];
    const float* fh_w2  = (const float*)d_in[11];
    const float* fh_b2  = (const float*)d_in[12];
    const float* l1w    = (const float*)d_in[13];
    const float* l1b    = (const float*)d_in[14];
    const float* l2w    = (const float*)d_in[15];
    const float* l2b    = (const float*)d_in[16];
    const float* l3w    = (const float*)d_in[17];
    const float* l3b    = (const float*)d_in[18];
    const float* l4w    = (const float*)d_in[19];
    const float* l4b    = (const float*)d_in[20];
    const float* l5w    = (const float*)d_in[21];
    const float* l5b    = (const float*)d_in[22];
    float* out = (float*)d_out;

    const int n_edges = in_sizes[2] / 2;             // 600000
    const int n_nodes = in_sizes[0] / HID;           // 100000
    const int nsb     = (n_nodes + 255) / 256;       // 391 scan blocks

    char* ws = (char*)d_ws;
    const bool use_csr = (ws_size >= 208800000ULL);

    if (use_csr) {
        u16* g    = (u16*)(ws + 0);                  // 153,600,000 B
        u16* xb   = (u16*)(ws + 153600000);          //  25,600,000 B
        u16* m_i  = (u16*)(ws + 179200000);          //  25,600,000 B (bf16)
        u16* w1t  = (u16*)(ws + 204800000);
        u16* w2t  = (u16*)(ws + 204865536);
        u16* fh1t = (u16*)(ws + 204898304);
        u16* fh2t = (u16*)(ws + 204963840);
        u16* l1t  = (u16*)(ws + 204996608);
        u16* l2t  = (u16*)(ws + 205029376);
        u16* l3t  = (u16*)(ws + 205062144);
        u16* l4t  = (u16*)(ws + 205094912);
        int* cnt  = (int*)(ws + 205127680);          // 400,000 B
        int* offs = (int*)(ws + 205527680);          // 400,016 B (N+1 ints)
        int* cur  = (int*)(ws + 205927696);          // 400,000 B
        int* perm = (int*)(ws + 206327696);          // 2,400,000 B
        int* part = (int*)(ws + 208727696);          // scan partials

        (void)hipMemsetAsync(cnt, 0, (size_t)n_nodes * sizeof(int), stream);
        prep_x<<<dim3((n_nodes * HID) / (256 * 8)), dim3(256), 0, stream>>>(x, xb);
        prep_weights<<<dim3(640), dim3(256), 0, stream>>>(
            fe_w1, fh_w1, fe_w2, fh_w2, l1w, l2w, l3w, l4w,
            w1t, fh1t, w2t, fh2t, l1t, l2t, l3t, l4t);

        // CSR build (counting sort by source node); cnt doubles as scanout
        hist_kernel<<<dim3((n_edges + 255) / 256), dim3(256), 0, stream>>>(eidx, cnt, n_edges);
        scan1<<<dim3(nsb), dim3(256), 0, stream>>>(cnt, cnt, part, n_nodes);
        scan2<<<dim3(1), dim3(512), 0, stream>>>(part, nsb);
        scan3<<<dim3(nsb), dim3(256), 0, stream>>>(cnt, part, offs, cur, n_nodes, n_edges);
        reorder_kernel<<<dim3((n_edges + 255) / 256), dim3(256), 0, stream>>>(eidx, cur, perm, n_edges);

        egc_edge_csr<<<dim3(n_edges / 32), dim3(256), 0, stream>>>(
            xb, pos, eidx, eidx + n_edges, w1t, fe_w1 + (size_t)256 * HID, fe_b1,
            w2t, fe_b2, finf_w, finf_b, g);

        gather_kernel<<<dim3(n_nodes / 4), dim3(256), 0, stream>>>(g, perm, offs, m_i);

        egc_node_mfma<true><<<dim3(n_nodes / 32), dim3(256), 0, stream>>>(
            xb, x, m_i, fh1t, fh_b1, fh2t, fh_b2, l1t, l1b, l2t, l2b,
            l3t, l3b, l4t, l4b, l5w, l5b, out);
    } else {
        // fallback: round-3 fused atomic path (ws >= ~77.2 MB, proven)
        float* m_i = (float*)(ws + 0);               // 51,200,000 B
        u16* xb    = (u16*)(ws + 51200000);          // 25,600,000 B
        u16* w1t   = (u16*)(ws + 76800000);
        u16* w2t   = (u16*)(ws + 76865536);
        u16* fh1t  = (u16*)(ws + 76898304);
        u16* fh2t  = (u16*)(ws + 76963840);
        u16* l1t   = (u16*)(ws + 76996608);
        u16* l2t   = (u16*)(ws + 77029376);
        u16* l3t   = (u16*)(ws + 77062144);
        u16* l4t   = (u16*)(ws + 77094912);

        (void)hipMemsetAsync(m_i, 0, (size_t)n_nodes * HID * sizeof(float), stream);
        prep_x<<<dim3((n_nodes * HID) / (256 * 8)), dim3(256), 0, stream>>>(x, xb);
        prep_weights<<<dim3(640), dim3(256), 0, stream>>>(
            fe_w1, fh_w1, fe_w2, fh_w2, l1w, l2w, l3w, l4w,
            w1t, fh1t, w2t, fh2t, l1t, l2t, l3t, l4t);

        egc_edge_mfma<<<dim3(n_edges / 32), dim3(256), 0, stream>>>(
            xb, pos, eidx, eidx + n_edges, w1t, fe_w1 + (size_t)256 * HID, fe_b1,
            w2t, fe_b2, finf_w, finf_b, m_i);

        egc_node_mfma<false><<<dim3(n_nodes / 32), dim3(256), 0, stream>>>(
            xb, x, m_i, fh1t, fh_b1, fh2t, fh_b2, l1t, l1b, l2t, l2b,
            l3t, l3b, l4t, l4b, l5w, l5b, out);
    }
}

// Round 5
// 419.075 us; speedup vs baseline: 3.9801x; 1.2521x over previous
//
#include <hip/hip_runtime.h>
#include <math.h>

#define HID 128

typedef unsigned short u16;
typedef __attribute__((ext_vector_type(8))) short bfrag;      // 8 bf16 (4 VGPRs)
typedef __attribute__((ext_vector_type(4))) float f32x4;      // MFMA C/D
typedef __attribute__((ext_vector_type(8))) unsigned short u16x8;

__device__ __forceinline__ float fast_tanh(float v) {
    v = fminf(15.0f, fmaxf(-15.0f, v));
    float e = __expf(2.0f * v);
    return (e - 1.0f) / (e + 1.0f);
}

// fp32 -> bf16 round-to-nearest-even
__device__ __forceinline__ u16 f2b(float f) {
    union { float f; unsigned int u; } v;
    v.f = f;
    unsigned int u = v.u;
    return (u16)((u + 0x7FFFu + ((u >> 16) & 1u)) >> 16);
}
__device__ __forceinline__ float b2f(u16 b) {
    union { unsigned int u; float f; } v;
    v.u = ((unsigned int)b) << 16;
    return v.f;
}
__device__ __forceinline__ float bits2f(unsigned u) {
    union { unsigned u; float f; } v; v.u = u; return v.f;
}

// ---------------- prep: x -> bf16 ----------------
__global__ void __launch_bounds__(256) prep_x(const float* __restrict__ x,
                                              u16* __restrict__ xb) {
    int i = blockIdx.x * 256 + threadIdx.x;
    const float4 v0 = *(const float4*)(x + (size_t)i * 8);
    const float4 v1 = *(const float4*)(x + (size_t)i * 8 + 4);
    u16x8 o = { f2b(v0.x), f2b(v0.y), f2b(v0.z), f2b(v0.w),
                f2b(v1.x), f2b(v1.y), f2b(v1.z), f2b(v1.w) };
    *(u16x8*)(xb + (size_t)i * 8) = o;
}

// ---------------- prep: weights -> k-major bf16 ----------------
__global__ void __launch_bounds__(256) prep_weights(
    const float* __restrict__ w1, const float* __restrict__ fh1,
    const float* __restrict__ w2, const float* __restrict__ fh2,
    const float* __restrict__ l1, const float* __restrict__ l2,
    const float* __restrict__ l3, const float* __restrict__ l4,
    u16* __restrict__ w1t, u16* __restrict__ fh1t,
    u16* __restrict__ w2t, u16* __restrict__ fh2t,
    u16* __restrict__ l1t, u16* __restrict__ l2t,
    u16* __restrict__ l3t, u16* __restrict__ l4t)
{
    int b = blockIdx.x, t = threadIdx.x;
    const float* src; u16* dst; int K;
    if (b < 256) {
        K = 256;
        if (b < 128) { src = w1;  dst = w1t; }
        else         { src = fh1; dst = fh1t; b -= 128; }
    } else {
        K = 128;
        int s = (b - 256) >> 6; b = (b - 256) & 63;
        switch (s) {
            case 0:  src = w2;  dst = w2t;  break;
            case 1:  src = fh2; dst = fh2t; break;
            case 2:  src = l1;  dst = l1t;  break;
            case 3:  src = l2;  dst = l2t;  break;
            case 4:  src = l3;  dst = l3t;  break;
            default: src = l4;  dst = l4t;  break;
        }
    }
    int idx = b * 256 + t;
    int k = idx >> 7, n = idx & 127;
    dst[(size_t)n * K + k] = f2b(src[(size_t)k * 128 + n]);
}

// ---------------- CSR build: hist / scan / reorder(inv) ----------------
__global__ void __launch_bounds__(256) hist_kernel(const int* __restrict__ est,
                                                   int* __restrict__ cnt, int E) {
    int e = blockIdx.x * 256 + threadIdx.x;
    if (e < E) atomicAdd(&cnt[est[e]], 1);
}

__global__ void __launch_bounds__(256) scan1(const int* __restrict__ cnt,
                                             int* __restrict__ scanout,
                                             int* __restrict__ partial, int N) {
    __shared__ int s[256];
    int t = threadIdx.x, b = blockIdx.x, i = b * 256 + t;
    int v = (i < N) ? cnt[i] : 0;
    s[t] = v; __syncthreads();
#pragma unroll
    for (int d = 1; d < 256; d <<= 1) {
        int add = (t >= d) ? s[t - d] : 0;
        __syncthreads();
        s[t] += add;
        __syncthreads();
    }
    if (i < N) scanout[i] = s[t] - v;
    if (t == 255) partial[b] = s[255];
}

__global__ void __launch_bounds__(512) scan2(int* __restrict__ partial, int NB) {
    __shared__ int s[512];
    int t = threadIdx.x;
    int v = (t < NB) ? partial[t] : 0;
    s[t] = v; __syncthreads();
#pragma unroll
    for (int d = 1; d < 512; d <<= 1) {
        int add = (t >= d) ? s[t - d] : 0;
        __syncthreads();
        s[t] += add;
        __syncthreads();
    }
    if (t < NB) partial[t] = s[t] - v;
}

__global__ void __launch_bounds__(256) scan3(const int* __restrict__ scanout,
                                             const int* __restrict__ partial,
                                             int* __restrict__ offs,
                                             int* __restrict__ cur, int N, int E) {
    int t = threadIdx.x, b = blockIdx.x, i = b * 256 + t;
    if (i < N) { int o = scanout[i] + partial[b]; offs[i] = o; cur[i] = o; }
    if (i == 0) offs[N] = E;
}

__global__ void __launch_bounds__(256) reorder_kernel(const int* __restrict__ est,
                                                      int* __restrict__ cur,
                                                      int* __restrict__ inv, int E) {
    int e = blockIdx.x * 256 + threadIdx.x;
    if (e < E) { int p = atomicAdd(&cur[est[e]], 1); inv[e] = p; }
}

// ---------------- shared GEMM tile (LDS A x global B) — used by node/fallback ----------------
template<int KD>
__device__ __forceinline__ void gemm_k(const u16* sbuf, const u16* __restrict__ wt,
                                       int w, int l16, int l4g, f32x4 (&acc)[2][2]) {
    const int RS = KD * 2;
#pragma unroll
    for (int k0 = 0; k0 < KD; k0 += 32) {
        const int kb = k0 * 2 + l4g * 16;
        bfrag a0 = *(const bfrag*)((const char*)sbuf +
                    (unsigned)((l16 * RS + kb) ^ ((l16 & 7) << 4)));
        bfrag a1 = *(const bfrag*)((const char*)sbuf +
                    (unsigned)(((16 + l16) * RS + kb) ^ ((l16 & 7) << 4)));
        bfrag b0 = *(const bfrag*)((const char*)wt + (size_t)(32 * w + l16) * RS + kb);
        bfrag b1 = *(const bfrag*)((const char*)wt + (size_t)(32 * w + 16 + l16) * RS + kb);
        acc[0][0] = __builtin_amdgcn_mfma_f32_16x16x32_bf16(a0, b0, acc[0][0], 0, 0, 0);
        acc[0][1] = __builtin_amdgcn_mfma_f32_16x16x32_bf16(a0, b1, acc[0][1], 0, 0, 0);
        acc[1][0] = __builtin_amdgcn_mfma_f32_16x16x32_bf16(a1, b0, acc[1][0], 0, 0, 0);
        acc[1][1] = __builtin_amdgcn_mfma_f32_16x16x32_bf16(a1, b1, acc[1][1], 0, 0, 0);
    }
}

// ---------------- edge kernel: persistent, weights in VGPRs, inv-permuted store ----------------
__global__ void __launch_bounds__(256, 2)
egc_edge_csr(const u16* __restrict__ xb, const float* __restrict__ pos,
             const int* __restrict__ est, const int* __restrict__ eend,
             const int* __restrict__ inv,
             const u16* __restrict__ w1t, const float* __restrict__ w1last,
             const float* __restrict__ b1, const u16* __restrict__ w2t,
             const float* __restrict__ b2, const float* __restrict__ fw,
             const float* __restrict__ fb, u16* __restrict__ g, int n_tiles)
{
    __shared__ __attribute__((aligned(16))) u16 a_sh[2][32 * 256];  // 32 KB dbuf, swz
    __shared__ __attribute__((aligned(16))) u16 m1_sh[32 * 128];    // 8 KB, swz
    __shared__ __attribute__((aligned(16))) u16 m2_sh[32][136];     // 8.5 KB, linear
    __shared__ float dist_l[2][32];
    __shared__ int   dst_l[2][32];
    __shared__ float ev_l[32];
    __shared__ float fw_l[128];

    const int t = threadIdx.x, lane = t & 63, w = t >> 6;
    const int l16 = lane & 15, l4g = lane >> 4;

    // ---- hoist weight B-fragments into registers (once per block) ----
    bfrag w1f0[8], w1f1[8], w2f0[4], w2f1[4];
#pragma unroll
    for (int i = 0; i < 8; ++i) {
        int kb = i * 64 + l4g * 16;
        w1f0[i] = *(const bfrag*)((const char*)w1t + (size_t)(32 * w + l16) * 512 + kb);
        w1f1[i] = *(const bfrag*)((const char*)w1t + (size_t)(32 * w + 16 + l16) * 512 + kb);
    }
#pragma unroll
    for (int i = 0; i < 4; ++i) {
        int kb = i * 64 + l4g * 16;
        w2f0[i] = *(const bfrag*)((const char*)w2t + (size_t)(32 * w + l16) * 256 + kb);
        w2f1[i] = *(const bfrag*)((const char*)w2t + (size_t)(32 * w + 16 + l16) * 256 + kb);
    }
    float wl[2], c1[2], c2[2];
#pragma unroll
    for (int ni = 0; ni < 2; ++ni) {
        int col = 32 * w + 16 * ni + l16;
        wl[ni] = w1last[col]; c1[ni] = b1[col]; c2[ni] = b2[col];
    }
    if (t < 128) fw_l[t] = fw[t];
    const float fbv = fb[0];

    // ---- staging registers ----
    float4 sv0, sv1, sv2, sv3;
    float pax = 0, pay = 0, paz = 0, pbx = 0, pby = 0, pbz = 0;
    int sdst = 0;

#define EDGE_ISSUE(TILE) do {                                                  \
        int e0_ = (TILE) * 32;                                                 \
        { int f_ = t;       int e_ = f_ >> 5, q_ = f_ & 31; int ge_ = e0_ + e_;\
          int nd_ = (q_ < 16) ? est[ge_] : eend[ge_];                          \
          sv0 = *(const float4*)(xb + (size_t)nd_ * 128 + (q_ & 15) * 8); }    \
        { int f_ = t + 256; int e_ = f_ >> 5, q_ = f_ & 31; int ge_ = e0_ + e_;\
          int nd_ = (q_ < 16) ? est[ge_] : eend[ge_];                          \
          sv1 = *(const float4*)(xb + (size_t)nd_ * 128 + (q_ & 15) * 8); }    \
        { int f_ = t + 512; int e_ = f_ >> 5, q_ = f_ & 31; int ge_ = e0_ + e_;\
          int nd_ = (q_ < 16) ? est[ge_] : eend[ge_];                          \
          sv2 = *(const float4*)(xb + (size_t)nd_ * 128 + (q_ & 15) * 8); }    \
        { int f_ = t + 768; int e_ = f_ >> 5, q_ = f_ & 31; int ge_ = e0_ + e_;\
          int nd_ = (q_ < 16) ? est[ge_] : eend[ge_];                          \
          sv3 = *(const float4*)(xb + (size_t)nd_ * 128 + (q_ & 15) * 8); }    \
        if (t < 32) {                                                          \
            int ge_ = e0_ + t;                                                 \
            int a_ = est[ge_], b_ = eend[ge_];                                 \
            sdst = inv[ge_];                                                   \
            pax = pos[a_ * 3]; pay = pos[a_ * 3 + 1]; paz = pos[a_ * 3 + 2];   \
            pbx = pos[b_ * 3]; pby = pos[b_ * 3 + 1]; pbz = pos[b_ * 3 + 2];   \
        }                                                                      \
    } while (0)

#define EDGE_COMMIT(BUF) do {                                                  \
        { int f_ = t;       int e_ = f_ >> 5, q_ = f_ & 31;                    \
          unsigned by_ = (unsigned)(e_ * 512 + q_ * 16) ^ (unsigned)((e_ & 7) << 4); \
          *(float4*)((char*)a_sh[BUF] + by_) = sv0; }                          \
        { int f_ = t + 256; int e_ = f_ >> 5, q_ = f_ & 31;                    \
          unsigned by_ = (unsigned)(e_ * 512 + q_ * 16) ^ (unsigned)((e_ & 7) << 4); \
          *(float4*)((char*)a_sh[BUF] + by_) = sv1; }                          \
        { int f_ = t + 512; int e_ = f_ >> 5, q_ = f_ & 31;                    \
          unsigned by_ = (unsigned)(e_ * 512 + q_ * 16) ^ (unsigned)((e_ & 7) << 4); \
          *(float4*)((char*)a_sh[BUF] + by_) = sv2; }                          \
        { int f_ = t + 768; int e_ = f_ >> 5, q_ = f_ & 31;                    \
          unsigned by_ = (unsigned)(e_ * 512 + q_ * 16) ^ (unsigned)((e_ & 7) << 4); \
          *(float4*)((char*)a_sh[BUF] + by_) = sv3; }                          \
        if (t < 32) {                                                          \
            float dx_ = pax - pbx, dy_ = pay - pby, dz_ = paz - pbz;           \
            dx_ *= dx_; dy_ *= dy_; dz_ *= dz_;                                \
            dist_l[BUF][t] = sqrtf(dx_ * dx_ + dy_ * dy_ + dz_ * dz_);         \
            dst_l[BUF][t] = sdst;                                              \
        }                                                                      \
    } while (0)

    int tile = blockIdx.x;
    EDGE_ISSUE(tile);
    int buf = 0;

    while (true) {
        EDGE_COMMIT(buf);
        __syncthreads();
        int next = tile + gridDim.x;
        if (next < n_tiles) EDGE_ISSUE(next);

        // ---- GEMM1: K=256, B from regs ----
        {
            f32x4 acc[2][2] = {};
#pragma unroll
            for (int i = 0; i < 8; ++i) {
                int kb = i * 64 + l4g * 16;
                bfrag a0 = *(const bfrag*)((const char*)a_sh[buf] +
                            (unsigned)((l16 * 512 + kb) ^ ((l16 & 7) << 4)));
                bfrag a1 = *(const bfrag*)((const char*)a_sh[buf] +
                            (unsigned)(((16 + l16) * 512 + kb) ^ ((l16 & 7) << 4)));
                acc[0][0] = __builtin_amdgcn_mfma_f32_16x16x32_bf16(a0, w1f0[i], acc[0][0], 0, 0, 0);
                acc[0][1] = __builtin_amdgcn_mfma_f32_16x16x32_bf16(a0, w1f1[i], acc[0][1], 0, 0, 0);
                acc[1][0] = __builtin_amdgcn_mfma_f32_16x16x32_bf16(a1, w1f0[i], acc[1][0], 0, 0, 0);
                acc[1][1] = __builtin_amdgcn_mfma_f32_16x16x32_bf16(a1, w1f1[i], acc[1][1], 0, 0, 0);
            }
#pragma unroll
            for (int mi = 0; mi < 2; ++mi)
#pragma unroll
                for (int ni = 0; ni < 2; ++ni) {
                    const int col = 32 * w + 16 * ni + l16;
#pragma unroll
                    for (int rg = 0; rg < 4; ++rg) {
                        const int row = 16 * mi + l4g * 4 + rg;
                        float v = fast_tanh(acc[mi][ni][rg] + dist_l[buf][row] * wl[ni] + c1[ni]);
                        unsigned byte = (unsigned)((row * 256 + col * 2) ^ ((row & 7) << 4));
                        *(u16*)((char*)m1_sh + byte) = f2b(v);
                    }
                }
        }
        __syncthreads();

        // ---- GEMM2: K=128, B from regs ----
        {
            f32x4 acc[2][2] = {};
#pragma unroll
            for (int i = 0; i < 4; ++i) {
                int kb = i * 64 + l4g * 16;
                bfrag a0 = *(const bfrag*)((const char*)m1_sh +
                            (unsigned)((l16 * 256 + kb) ^ ((l16 & 7) << 4)));
                bfrag a1 = *(const bfrag*)((const char*)m1_sh +
                            (unsigned)(((16 + l16) * 256 + kb) ^ ((l16 & 7) << 4)));
                acc[0][0] = __builtin_amdgcn_mfma_f32_16x16x32_bf16(a0, w2f0[i], acc[0][0], 0, 0, 0);
                acc[0][1] = __builtin_amdgcn_mfma_f32_16x16x32_bf16(a0, w2f1[i], acc[0][1], 0, 0, 0);
                acc[1][0] = __builtin_amdgcn_mfma_f32_16x16x32_bf16(a1, w2f0[i], acc[1][0], 0, 0, 0);
                acc[1][1] = __builtin_amdgcn_mfma_f32_16x16x32_bf16(a1, w2f1[i], acc[1][1], 0, 0, 0);
            }
#pragma unroll
            for (int mi = 0; mi < 2; ++mi)
#pragma unroll
                for (int ni = 0; ni < 2; ++ni) {
                    const int col = 32 * w + 16 * ni + l16;
#pragma unroll
                    for (int rg = 0; rg < 4; ++rg) {
                        const int row = 16 * mi + l4g * 4 + rg;
                        m2_sh[row][col] = f2b(fast_tanh(acc[mi][ni][rg] + c2[ni]));
                    }
                }
        }
        __syncthreads();

        // ---- gate: e = tanh(m2 . fw + fb), 4 threads/edge ----
        if (t < 128) {
            int e = t >> 2, p = t & 3;
            float s = 0.0f;
#pragma unroll
            for (int kk = 0; kk < 4; ++kk) {
                u16x8 mv = *(const u16x8*)&m2_sh[e][p * 32 + kk * 8];
#pragma unroll
                for (int q = 0; q < 8; ++q)
                    s += b2f(mv[q]) * fw_l[p * 32 + kk * 8 + q];
            }
            s += __shfl_xor(s, 1);
            s += __shfl_xor(s, 2);
            if (p == 0) ev_l[e] = fast_tanh(s + fbv);
        }
        __syncthreads();

        // ---- store at CSR position: g[inv[e]] = ev * m2[e] ----
        {
            int row = t >> 3, l8 = t & 7;
            float ev = ev_l[row];
            const u16* src = &m2_sh[row][16 * l8];
            u16x8 a = *(const u16x8*)src;
            u16x8 b = *(const u16x8*)(src + 8);
            u16x8 o0, o1;
#pragma unroll
            for (int q = 0; q < 8; ++q) {
                o0[q] = f2b(b2f(a[q]) * ev);
                o1[q] = f2b(b2f(b[q]) * ev);
            }
            u16* dst = g + (size_t)dst_l[buf][row] * 128 + 16 * l8;
            *(u16x8*)dst = o0;
            *(u16x8*)(dst + 8) = o1;
        }

        tile = next; buf ^= 1;
        if (tile >= n_tiles) break;
    }
#undef EDGE_ISSUE
#undef EDGE_COMMIT
}

// ---------------- gather: sequential CSR segments, coalesced ----------------
__global__ void __launch_bounds__(256, 8)
gather_seq(const u16* __restrict__ g, const int* __restrict__ offs,
           u16* __restrict__ m_i)
{
    const int lane = threadIdx.x & 63;
    const int n = blockIdx.x * 4 + (threadIdx.x >> 6);
    const int beg = offs[n], end = offs[n + 1];
    float a0 = 0.0f, a1 = 0.0f, b0 = 0.0f, b1 = 0.0f;
    int e = beg;
    for (; e + 1 < end; e += 2) {
        unsigned v0 = *(const unsigned*)(g + (size_t)e * 128 + lane * 2);
        unsigned v1 = *(const unsigned*)(g + (size_t)(e + 1) * 128 + lane * 2);
        a0 += bits2f(v0 << 16);
        a1 += bits2f(v0 & 0xFFFF0000u);
        b0 += bits2f(v1 << 16);
        b1 += bits2f(v1 & 0xFFFF0000u);
    }
    if (e < end) {
        unsigned v0 = *(const unsigned*)(g + (size_t)e * 128 + lane * 2);
        a0 += bits2f(v0 << 16);
        a1 += bits2f(v0 & 0xFFFF0000u);
    }
    a0 += b0; a1 += b1;
    unsigned o = (unsigned)f2b(a0) | ((unsigned)f2b(a1) << 16);
    ((unsigned*)m_i)[(size_t)n * 64 + lane] = o;
}

// ---------------- edge kernel, fallback atomic path (round-3, proven) ----------------
__global__ void __launch_bounds__(256, 3)
egc_edge_mfma(const u16* __restrict__ xb, const float* __restrict__ pos,
              const int* __restrict__ est, const int* __restrict__ eend,
              const u16* __restrict__ w1t, const float* __restrict__ w1last,
              const float* __restrict__ b1, const u16* __restrict__ w2t,
              const float* __restrict__ b2, const float* __restrict__ fw,
              const float* __restrict__ fb, float* __restrict__ m_i)
{
    __shared__ __attribute__((aligned(16))) u16 a_sh[32 * 256];
    __shared__ __attribute__((aligned(16))) u16 m1_sh[32 * 128];
    __shared__ float m2_sh[32][132];
    __shared__ float dist_l[32];
    __shared__ float ev_l[32];
    __shared__ int   st_l[32];

    const int t = threadIdx.x;
    const int e0 = blockIdx.x * 32;
    const int lane = t & 63;
    const int w = t >> 6;
    const int l16 = lane & 15, l4g = lane >> 4;

#pragma unroll
    for (int i = 0; i < 4; ++i) {
        int f = t + 256 * i;
        int e = f >> 5, q = f & 31;
        int ge = e0 + e;
        int node = (q < 16) ? est[ge] : eend[ge];
        float4 v = *(const float4*)(xb + (size_t)node * 128 + (q & 15) * 8);
        unsigned byte = (unsigned)(e * 512 + q * 16) ^ (unsigned)((e & 7) << 4);
        *(float4*)((char*)a_sh + byte) = v;
    }
    if (t < 32) {
        int ge = e0 + t;
        int a = est[ge], b = eend[ge];
        st_l[t] = a;
        float dx = pos[a * 3 + 0] - pos[b * 3 + 0];
        float dy = pos[a * 3 + 1] - pos[b * 3 + 1];
        float dz = pos[a * 3 + 2] - pos[b * 3 + 2];
        dx *= dx; dy *= dy; dz *= dz;
        dist_l[t] = sqrtf(dx * dx + dy * dy + dz * dz);
    }
    __syncthreads();

    {
        f32x4 acc[2][2] = {};
        gemm_k<256>(a_sh, w1t, w, l16, l4g, acc);
#pragma unroll
        for (int mi = 0; mi < 2; ++mi)
#pragma unroll
            for (int ni = 0; ni < 2; ++ni) {
                const int col = 32 * w + 16 * ni + l16;
                const float wl = w1last[col], bb = b1[col];
#pragma unroll
                for (int rg = 0; rg < 4; ++rg) {
                    const int row = 16 * mi + l4g * 4 + rg;
                    float v = fast_tanh(acc[mi][ni][rg] + dist_l[row] * wl + bb);
                    unsigned byte = (unsigned)((row * 256 + col * 2) ^ ((row & 7) << 4));
                    *(u16*)((char*)m1_sh + byte) = f2b(v);
                }
            }
    }
    __syncthreads();

    {
        f32x4 acc[2][2] = {};
        gemm_k<128>(m1_sh, w2t, w, l16, l4g, acc);
#pragma unroll
        for (int mi = 0; mi < 2; ++mi)
#pragma unroll
            for (int ni = 0; ni < 2; ++ni) {
                const int col = 32 * w + 16 * ni + l16;
                const float bb = b2[col];
#pragma unroll
                for (int rg = 0; rg < 4; ++rg) {
                    const int row = 16 * mi + l4g * 4 + rg;
                    m2_sh[row][col] = fast_tanh(acc[mi][ni][rg] + bb);
                }
            }
    }
    __syncthreads();

    if (t < 128) {
        int e = t >> 2, p = t & 3;
        float s = 0.0f;
#pragma unroll
        for (int k = 0; k < 32; ++k) s += m2_sh[e][p * 32 + k] * fw[p * 32 + k];
        s += __shfl_xor(s, 1);
        s += __shfl_xor(s, 2);
        if (p == 0) ev_l[e] = fast_tanh(s + fb[0]);
    }
    __syncthreads();

    {
        int e = t >> 3, l8 = t & 7;
        float ev = ev_l[e];
        size_t base = (size_t)st_l[e] * HID + l8;
#pragma unroll
        for (int i = 0; i < 16; ++i)
            unsafeAtomicAdd(m_i + base + 8 * i, ev * m2_sh[e][l8 + 8 * i]);
    }
}

// ---------------- node kernel ----------------
#define NODE_LAYER(SRC, KD, WT, BIAS, EPILOG)                                  \
    {                                                                          \
        f32x4 acc[2][2] = {};                                                  \
        gemm_k<KD>(SRC, WT, w, l16, l4g, acc);                                 \
        _Pragma("unroll")                                                      \
        for (int mi = 0; mi < 2; ++mi)                                         \
            _Pragma("unroll")                                                  \
            for (int ni = 0; ni < 2; ++ni) {                                   \
                const int col = 32 * w + 16 * ni + l16;                        \
                const float bb = (BIAS)[col];                                  \
                _Pragma("unroll")                                              \
                for (int rg = 0; rg < 4; ++rg) {                               \
                    const int row = 16 * mi + l4g * 4 + rg;                    \
                    float v = acc[mi][ni][rg] + bb;                            \
                    EPILOG;                                                    \
                }                                                              \
            }                                                                  \
    }

#define STORE_BF16(DST) do {                                                   \
        unsigned byte = (unsigned)((row * 256 + col * 2) ^ ((row & 7) << 4));  \
        *(u16*)((char*)(DST) + byte) = f2b(v);                                 \
    } while (0)

template<bool MIBF16>
__global__ void __launch_bounds__(256, 3)
egc_node_mfma(const u16* __restrict__ xb, const float* __restrict__ xf,
              const void* __restrict__ m_i,
              const u16* __restrict__ fh1t, const float* __restrict__ hb1,
              const u16* __restrict__ fh2t, const float* __restrict__ hb2,
              const u16* __restrict__ l1t, const float* __restrict__ l1b,
              const u16* __restrict__ l2t, const float* __restrict__ l2b,
              const u16* __restrict__ l3t, const float* __restrict__ l3b,
              const u16* __restrict__ l4t, const float* __restrict__ l4b,
              const float* __restrict__ l5w, const float* __restrict__ l5b,
              float* __restrict__ out)
{
    __shared__ __attribute__((aligned(16))) u16 a_sh[32 * 256];
    __shared__ __attribute__((aligned(16))) u16 bA[32 * 128];
    __shared__ __attribute__((aligned(16))) u16 bB[32 * 128];
    __shared__ float ff[32][132];

    const int t = threadIdx.x;
    const int n0 = blockIdx.x * 32;
    const int lane = t & 63;
    const int w = t >> 6;
    const int l16 = lane & 15, l4g = lane >> 4;

#pragma unroll
    for (int i = 0; i < 2; ++i) {
        int f = t + 256 * i;
        int n = f >> 4, q = f & 15;
        float4 v = *(const float4*)(xb + (size_t)(n0 + n) * 128 + q * 8);
        unsigned byte = (unsigned)((n * 512 + q * 16) ^ ((n & 7) << 4));
        *(float4*)((char*)a_sh + byte) = v;
    }
    if (MIBF16) {
#pragma unroll
        for (int i = 0; i < 2; ++i) {
            int f = t + 256 * i;
            int n = f >> 4, q = f & 15;
            float4 v = *(const float4*)((const u16*)m_i + (size_t)(n0 + n) * 128 + q * 8);
            unsigned byte = (unsigned)((n * 512 + 256 + q * 16) ^ ((n & 7) << 4));
            *(float4*)((char*)a_sh + byte) = v;
        }
    } else {
#pragma unroll
        for (int i = 0; i < 2; ++i) {
            int f = t + 256 * i;
            int n = f >> 4, q = f & 15;
            const float* src = (const float*)m_i + (size_t)(n0 + n) * 128 + q * 8;
            float4 v0 = *(const float4*)(src);
            float4 v1 = *(const float4*)(src + 4);
            u16x8 o = { f2b(v0.x), f2b(v0.y), f2b(v0.z), f2b(v0.w),
                        f2b(v1.x), f2b(v1.y), f2b(v1.z), f2b(v1.w) };
            unsigned byte = (unsigned)((n * 512 + 256 + q * 16) ^ ((n & 7) << 4));
            *(u16x8*)((char*)a_sh + byte) = o;
        }
    }
    __syncthreads();

    NODE_LAYER(a_sh, 256, fh1t, hb1, { v = fast_tanh(v); STORE_BF16(bA); })
    __syncthreads();
    NODE_LAYER(bA, 128, fh2t, hb2,
               { v += xf[(size_t)(n0 + row) * HID + col]; STORE_BF16(bB); })
    __syncthreads();
    NODE_LAYER(bB, 128, l1t, l1b, { v = v > 0.0f ? v : 0.01f * v; STORE_BF16(bA); })
    __syncthreads();
    NODE_LAYER(bA, 128, l2t, l2b, { v = v > 0.0f ? v : 0.01f * v; STORE_BF16(bB); })
    __syncthreads();
    NODE_LAYER(bB, 128, l3t, l3b, { v = v > 0.0f ? v : 0.01f * v; STORE_BF16(bA); })
    __syncthreads();
    NODE_LAYER(bA, 128, l4t, l4b, { ff[row][col] = v > 0.0f ? v : 0.01f * v; })
    __syncthreads();

    if (t < 96) {
        int n = t / 3, cc = t % 3;
        float s = l5b[cc];
#pragma unroll 8
        for (int k = 0; k < HID; ++k) s += ff[n][k] * l5w[k * 3 + cc];
        out[(size_t)(n0 + n) * 3 + cc] = s;
    }
}

extern "C" void kernel_launch(void* const* d_in, const int* in_sizes, int n_in,
                              void* d_out, int out_size, void* d_ws, size_t ws_size,
                              hipStream_t stream)
{
    const float* x      = (const float*)d_in[0];
    const float* pos    = (const float*)d_in[1];
    const int*   eidx   = (const int*)d_in[2];
    const float* fe_w1  = (const float*)d_in[3];
    const float* fe_b1  = (const float*)d_in[4];
    const float* fe_w2  = (const float*)d_in[5];
    const float* fe_b2  = (const float*)d_in[6];
    const float* finf_w = (const float*)d_in[7];
    const float* finf_b = (const float*)d_in[8];
    const float* fh_w1  = (const float*)d_in[9];
    const float* fh_b1  = (const float*)d_in[10];
    const float* fh_w2  = (const float*)d_in[11];
    const float* fh_b2  = (const float*)d_in[12];
    const float* l1w    = (const float*)d_in[13];
    const float* l1b    = (const float*)d_in[14];
    const float* l2w    = (const float*)d_in[15];
    const float* l2b    = (const float*)d_in[16];
    const float* l3w    = (const float*)d_in[17];
    const float* l3b    = (const float*)d_in[18];
    const float* l4w    = (const float*)d_in[19];
    const float* l4b    = (const float*)d_in[20];
    const float* l5w    = (const float*)d_in[21];
    const float* l5b    = (const float*)d_in[22];
    float* out = (float*)d_out;

    const int n_edges = in_sizes[2] / 2;             // 600000
    const int n_nodes = in_sizes[0] / HID;           // 100000
    const int nsb     = (n_nodes + 255) / 256;       // 391 scan blocks
    const int n_tiles = n_edges / 32;                // 18750

    char* ws = (char*)d_ws;
    const bool use_csr = (ws_size >= 208800000ULL);

    if (use_csr) {
        u16* g    = (u16*)(ws + 0);                  // 153,600,000 B
        u16* xb   = (u16*)(ws + 153600000);          //  25,600,000 B
        u16* m_i  = (u16*)(ws + 179200000);          //  25,600,000 B (bf16)
        u16* w1t  = (u16*)(ws + 204800000);
        u16* w2t  = (u16*)(ws + 204865536);
        u16* fh1t = (u16*)(ws + 204898304);
        u16* fh2t = (u16*)(ws + 204963840);
        u16* l1t  = (u16*)(ws + 204996608);
        u16* l2t  = (u16*)(ws + 205029376);
        u16* l3t  = (u16*)(ws + 205062144);
        u16* l4t  = (u16*)(ws + 205094912);
        int* cnt  = (int*)(ws + 205127680);          // 400,000 B
        int* offs = (int*)(ws + 205527680);          // 400,016 B (N+1 ints)
        int* cur  = (int*)(ws + 205927696);          // 400,000 B
        int* inv  = (int*)(ws + 206327696);          // 2,400,000 B
        int* part = (int*)(ws + 208727696);          // scan partials

        (void)hipMemsetAsync(cnt, 0, (size_t)n_nodes * sizeof(int), stream);
        prep_x<<<dim3((n_nodes * HID) / (256 * 8)), dim3(256), 0, stream>>>(x, xb);
        prep_weights<<<dim3(640), dim3(256), 0, stream>>>(
            fe_w1, fh_w1, fe_w2, fh_w2, l1w, l2w, l3w, l4w,
            w1t, fh1t, w2t, fh2t, l1t, l2t, l3t, l4t);

        hist_kernel<<<dim3((n_edges + 255) / 256), dim3(256), 0, stream>>>(eidx, cnt, n_edges);
        scan1<<<dim3(nsb), dim3(256), 0, stream>>>(cnt, cnt, part, n_nodes);
        scan2<<<dim3(1), dim3(512), 0, stream>>>(part, nsb);
        scan3<<<dim3(nsb), dim3(256), 0, stream>>>(cnt, part, offs, cur, n_nodes, n_edges);
        reorder_kernel<<<dim3((n_edges + 255) / 256), dim3(256), 0, stream>>>(eidx, cur, inv, n_edges);

        egc_edge_csr<<<dim3(512), dim3(256), 0, stream>>>(
            xb, pos, eidx, eidx + n_edges, inv, w1t, fe_w1 + (size_t)256 * HID, fe_b1,
            w2t, fe_b2, finf_w, finf_b, g, n_tiles);

        gather_seq<<<dim3(n_nodes / 4), dim3(256), 0, stream>>>(g, offs, m_i);

        egc_node_mfma<true><<<dim3(n_nodes / 32), dim3(256), 0, stream>>>(
            xb, x, m_i, fh1t, fh_b1, fh2t, fh_b2, l1t, l1b, l2t, l2b,
            l3t, l3b, l4t, l4b, l5w, l5b, out);
    } else {
        // fallback: round-3 fused atomic path
        float* m_i = (float*)(ws + 0);
        u16* xb    = (u16*)(ws + 51200000);
        u16* w1t   = (u16*)(ws + 76800000);
        u16* w2t   = (u16*)(ws + 76865536);
        u16* fh1t  = (u16*)(ws + 76898304);
        u16* fh2t  = (u16*)(ws + 76963840);
        u16* l1t   = (u16*)(ws + 76996608);
        u16* l2t   = (u16*)(ws + 77029376);
        u16* l3t   = (u16*)(ws + 77062144);
        u16* l4t   = (u16*)(ws + 77094912);

        (void)hipMemsetAsync(m_i, 0, (size_t)n_nodes * HID * sizeof(float), stream);
        prep_x<<<dim3((n_nodes * HID) / (256 * 8)), dim3(256), 0, stream>>>(x, xb);
        prep_weights<<<dim3(640), dim3(256), 0, stream>>>(
            fe_w1, fh_w1, fe_w2, fh_w2, l1w, l2w, l3w, l4w,
            w1t, fh1t, w2t, fh2t, l1t, l2t, l3t, l4t);

        egc_edge_mfma<<<dim3(n_edges / 32), dim3(256), 0, stream>>>(
            xb, pos, eidx, eidx + n_edges, w1t, fe_w1 + (size_t)256 * HID, fe_b1,
            w2t, fe_b2, finf_w, finf_b, m_i);

        egc_node_mfma<false><<<dim3(n_nodes / 32), dim3(256), 0, stream>>>(
            xb, x, m_i, fh1t, fh_b1, fh2t, fh_b2, l1t, l1b, l2t, l2b,
            l3t, l3b, l4t, l4b, l5w, l5b, out);
    }
}

// Round 6
// 384.345 us; speedup vs baseline: 4.3397x; 1.0904x over previous
//
#include <hip/hip_runtime.h>
#include <math.h>

#define HID 128

typedef unsigned short u16;
typedef __attribute__((ext_vector_type(8))) short bfrag;      // 8 bf16 (4 VGPRs)
typedef __attribute__((ext_vector_type(4))) float f32x4;      // MFMA C/D
typedef __attribute__((ext_vector_type(8))) unsigned short u16x8;
typedef __attribute__((ext_vector_type(4))) unsigned short u16x4;

__device__ __forceinline__ float fast_tanh(float v) {
    v = fminf(15.0f, fmaxf(-15.0f, v));
    float e = __expf(2.0f * v);
    float r = __builtin_amdgcn_rcpf(e + 1.0f);
    return 1.0f - 2.0f * r;
}

// fp32 -> bf16 round-to-nearest-even
__device__ __forceinline__ u16 f2b(float f) {
    union { float f; unsigned int u; } v;
    v.f = f;
    unsigned int u = v.u;
    return (u16)((u + 0x7FFFu + ((u >> 16) & 1u)) >> 16);
}
__device__ __forceinline__ float b2f(u16 b) {
    union { unsigned int u; float f; } v;
    v.u = ((unsigned int)b) << 16;
    return v.f;
}
__device__ __forceinline__ float bits2f(unsigned u) {
    union { unsigned u; float f; } v; v.u = u; return v.f;
}

// ---------------- prep: x -> bf16 ----------------
__global__ void __launch_bounds__(256) prep_x(const float* __restrict__ x,
                                              u16* __restrict__ xb) {
    int i = blockIdx.x * 256 + threadIdx.x;
    const float4 v0 = *(const float4*)(x + (size_t)i * 8);
    const float4 v1 = *(const float4*)(x + (size_t)i * 8 + 4);
    u16x8 o = { f2b(v0.x), f2b(v0.y), f2b(v0.z), f2b(v0.w),
                f2b(v1.x), f2b(v1.y), f2b(v1.z), f2b(v1.w) };
    *(u16x8*)(xb + (size_t)i * 8) = o;
}

// ---------------- prep: weights -> k-major bf16 ----------------
__global__ void __launch_bounds__(256) prep_weights(
    const float* __restrict__ w1, const float* __restrict__ fh1,
    const float* __restrict__ w2, const float* __restrict__ fh2,
    const float* __restrict__ l1, const float* __restrict__ l2,
    const float* __restrict__ l3, const float* __restrict__ l4,
    u16* __restrict__ w1t, u16* __restrict__ fh1t,
    u16* __restrict__ w2t, u16* __restrict__ fh2t,
    u16* __restrict__ l1t, u16* __restrict__ l2t,
    u16* __restrict__ l3t, u16* __restrict__ l4t)
{
    int b = blockIdx.x, t = threadIdx.x;
    const float* src; u16* dst; int K;
    if (b < 256) {
        K = 256;
        if (b < 128) { src = w1;  dst = w1t; }
        else         { src = fh1; dst = fh1t; b -= 128; }
    } else {
        K = 128;
        int s = (b - 256) >> 6; b = (b - 256) & 63;
        switch (s) {
            case 0:  src = w2;  dst = w2t;  break;
            case 1:  src = fh2; dst = fh2t; break;
            case 2:  src = l1;  dst = l1t;  break;
            case 3:  src = l2;  dst = l2t;  break;
            case 4:  src = l3;  dst = l3t;  break;
            default: src = l4;  dst = l4t;  break;
        }
    }
    int idx = b * 256 + t;
    int k = idx >> 7, n = idx & 127;
    dst[(size_t)n * K + k] = f2b(src[(size_t)k * 128 + n]);
}

// ---------------- CSR build: hist / scan / reorder(inv) ----------------
__global__ void __launch_bounds__(256) hist_kernel(const int* __restrict__ est,
                                                   int* __restrict__ cnt, int E) {
    int e = blockIdx.x * 256 + threadIdx.x;
    if (e < E) atomicAdd(&cnt[est[e]], 1);
}

__global__ void __launch_bounds__(256) scan1(const int* __restrict__ cnt,
                                             int* __restrict__ scanout,
                                             int* __restrict__ partial, int N) {
    __shared__ int s[256];
    int t = threadIdx.x, b = blockIdx.x, i = b * 256 + t;
    int v = (i < N) ? cnt[i] : 0;
    s[t] = v; __syncthreads();
#pragma unroll
    for (int d = 1; d < 256; d <<= 1) {
        int add = (t >= d) ? s[t - d] : 0;
        __syncthreads();
        s[t] += add;
        __syncthreads();
    }
    if (i < N) scanout[i] = s[t] - v;
    if (t == 255) partial[b] = s[255];
}

__global__ void __launch_bounds__(512) scan2(int* __restrict__ partial, int NB) {
    __shared__ int s[512];
    int t = threadIdx.x;
    int v = (t < NB) ? partial[t] : 0;
    s[t] = v; __syncthreads();
#pragma unroll
    for (int d = 1; d < 512; d <<= 1) {
        int add = (t >= d) ? s[t - d] : 0;
        __syncthreads();
        s[t] += add;
        __syncthreads();
    }
    if (t < NB) partial[t] = s[t] - v;
}

__global__ void __launch_bounds__(256) scan3(const int* __restrict__ scanout,
                                             const int* __restrict__ partial,
                                             int* __restrict__ offs,
                                             int* __restrict__ cur, int N, int E) {
    int t = threadIdx.x, b = blockIdx.x, i = b * 256 + t;
    if (i < N) { int o = scanout[i] + partial[b]; offs[i] = o; cur[i] = o; }
    if (i == 0) offs[N] = E;
}

__global__ void __launch_bounds__(256) reorder_kernel(const int* __restrict__ est,
                                                      int* __restrict__ cur,
                                                      int* __restrict__ inv, int E) {
    int e = blockIdx.x * 256 + threadIdx.x;
    if (e < E) { int p = atomicAdd(&cur[est[e]], 1); inv[e] = p; }
}

// ---------------- shared GEMM tile (LDS A x global B) — node/fallback ----------------
template<int KD>
__device__ __forceinline__ void gemm_k(const u16* sbuf, const u16* __restrict__ wt,
                                       int w, int l16, int l4g, f32x4 (&acc)[2][2]) {
    const int RS = KD * 2;
#pragma unroll
    for (int k0 = 0; k0 < KD; k0 += 32) {
        const int kb = k0 * 2 + l4g * 16;
        bfrag a0 = *(const bfrag*)((const char*)sbuf +
                    (unsigned)((l16 * RS + kb) ^ ((l16 & 7) << 4)));
        bfrag a1 = *(const bfrag*)((const char*)sbuf +
                    (unsigned)(((16 + l16) * RS + kb) ^ ((l16 & 7) << 4)));
        bfrag b0 = *(const bfrag*)((const char*)wt + (size_t)(32 * w + l16) * RS + kb);
        bfrag b1 = *(const bfrag*)((const char*)wt + (size_t)(32 * w + 16 + l16) * RS + kb);
        acc[0][0] = __builtin_amdgcn_mfma_f32_16x16x32_bf16(a0, b0, acc[0][0], 0, 0, 0);
        acc[0][1] = __builtin_amdgcn_mfma_f32_16x16x32_bf16(a0, b1, acc[0][1], 0, 0, 0);
        acc[1][0] = __builtin_amdgcn_mfma_f32_16x16x32_bf16(a1, b0, acc[1][0], 0, 0, 0);
        acc[1][1] = __builtin_amdgcn_mfma_f32_16x16x32_bf16(a1, b1, acc[1][1], 0, 0, 0);
    }
}

// ---------------- edge kernel: persistent, swapped-operand, gate deferred ----------------
// Swapped orientation: D[n][e] = mfma(A=weight rows n (regs), B=edge rows e (LDS)).
// C/D layout (m89): col = lane&15 -> e, row = (lane>>4)*4+rg -> n (4 consecutive
// output channels per lane) => 8 B vector epilogue stores instead of 32 scalars.
// g holds UNSCALED m_ij; the e_ij gate is computed in gather_gate.
__global__ void __launch_bounds__(256, 2)
egc_edge_csr(const u16* __restrict__ xb, const float* __restrict__ pos,
             const int* __restrict__ est, const int* __restrict__ eend,
             const int* __restrict__ inv,
             const u16* __restrict__ w1t, const float* __restrict__ w1last,
             const float* __restrict__ b1, const u16* __restrict__ w2t,
             const float* __restrict__ b2, u16* __restrict__ g, int n_tiles)
{
    __shared__ __attribute__((aligned(16))) u16 a_sh[2][32 * 256];  // 32 KB dbuf, swz
    __shared__ __attribute__((aligned(16))) u16 m1_sh[32 * 128];    // 8 KB, swz
    __shared__ float dist_l[2][32];
    __shared__ int   dst_l[2][32];

    const int t = threadIdx.x, lane = t & 63, w = t >> 6;
    const int l16 = lane & 15, l4g = lane >> 4;
    const unsigned swz = (unsigned)((l16 & 7) << 4);

    // ---- hoist weight A-fragments into registers (once per block) ----
    // wa1x[i] = w1 rows 32w(+16)+l16, k-chunk i ; w2x[i] same for w2.
    bfrag wa10[8], wa11[8], w2f0[4], w2f1[4];
#pragma unroll
    for (int i = 0; i < 8; ++i) {
        int kb = i * 64 + l4g * 16;
        wa10[i] = *(const bfrag*)((const char*)w1t + (size_t)(32 * w + l16) * 512 + kb);
        wa11[i] = *(const bfrag*)((const char*)w1t + (size_t)(32 * w + 16 + l16) * 512 + kb);
    }
#pragma unroll
    for (int i = 0; i < 4; ++i) {
        int kb = i * 64 + l4g * 16;
        w2f0[i] = *(const bfrag*)((const char*)w2t + (size_t)(32 * w + l16) * 256 + kb);
        w2f1[i] = *(const bfrag*)((const char*)w2t + (size_t)(32 * w + 16 + l16) * 256 + kb);
    }
    // per-lane output-channel constants: n = 32w + 16mi + l4g*4 + rg
    float w1l_r[2][4], b1_r[2][4], b2_r[2][4];
#pragma unroll
    for (int mi = 0; mi < 2; ++mi)
#pragma unroll
        for (int rg = 0; rg < 4; ++rg) {
            int n = 32 * w + 16 * mi + l4g * 4 + rg;
            w1l_r[mi][rg] = w1last[n];
            b1_r[mi][rg]  = b1[n];
            b2_r[mi][rg]  = b2[n];
        }

    // ---- staging registers ----
    float4 sv0, sv1, sv2, sv3;
    float pax = 0, pay = 0, paz = 0, pbx = 0, pby = 0, pbz = 0;
    int sdst = 0;

#define EDGE_ISSUE(TILE) do {                                                  \
        int e0_ = (TILE) * 32;                                                 \
        { int f_ = t;       int e_ = f_ >> 5, q_ = f_ & 31; int ge_ = e0_ + e_;\
          int nd_ = (q_ < 16) ? est[ge_] : eend[ge_];                          \
          sv0 = *(const float4*)(xb + (size_t)nd_ * 128 + (q_ & 15) * 8); }    \
        { int f_ = t + 256; int e_ = f_ >> 5, q_ = f_ & 31; int ge_ = e0_ + e_;\
          int nd_ = (q_ < 16) ? est[ge_] : eend[ge_];                          \
          sv1 = *(const float4*)(xb + (size_t)nd_ * 128 + (q_ & 15) * 8); }    \
        { int f_ = t + 512; int e_ = f_ >> 5, q_ = f_ & 31; int ge_ = e0_ + e_;\
          int nd_ = (q_ < 16) ? est[ge_] : eend[ge_];                          \
          sv2 = *(const float4*)(xb + (size_t)nd_ * 128 + (q_ & 15) * 8); }    \
        { int f_ = t + 768; int e_ = f_ >> 5, q_ = f_ & 31; int ge_ = e0_ + e_;\
          int nd_ = (q_ < 16) ? est[ge_] : eend[ge_];                          \
          sv3 = *(const float4*)(xb + (size_t)nd_ * 128 + (q_ & 15) * 8); }    \
        if (t < 32) {                                                          \
            int ge_ = e0_ + t;                                                 \
            int a_ = est[ge_], b_ = eend[ge_];                                 \
            sdst = inv[ge_];                                                   \
            pax = pos[a_ * 3]; pay = pos[a_ * 3 + 1]; paz = pos[a_ * 3 + 2];   \
            pbx = pos[b_ * 3]; pby = pos[b_ * 3 + 1]; pbz = pos[b_ * 3 + 2];   \
        }                                                                      \
    } while (0)

#define EDGE_COMMIT(BUF) do {                                                  \
        { int f_ = t;       int e_ = f_ >> 5, q_ = f_ & 31;                    \
          unsigned by_ = (unsigned)(e_ * 512 + q_ * 16) ^ (unsigned)((e_ & 7) << 4); \
          *(float4*)((char*)a_sh[BUF] + by_) = sv0; }                          \
        { int f_ = t + 256; int e_ = f_ >> 5, q_ = f_ & 31;                    \
          unsigned by_ = (unsigned)(e_ * 512 + q_ * 16) ^ (unsigned)((e_ & 7) << 4); \
          *(float4*)((char*)a_sh[BUF] + by_) = sv1; }                          \
        { int f_ = t + 512; int e_ = f_ >> 5, q_ = f_ & 31;                    \
          unsigned by_ = (unsigned)(e_ * 512 + q_ * 16) ^ (unsigned)((e_ & 7) << 4); \
          *(float4*)((char*)a_sh[BUF] + by_) = sv2; }                          \
        { int f_ = t + 768; int e_ = f_ >> 5, q_ = f_ & 31;                    \
          unsigned by_ = (unsigned)(e_ * 512 + q_ * 16) ^ (unsigned)((e_ & 7) << 4); \
          *(float4*)((char*)a_sh[BUF] + by_) = sv3; }                          \
        if (t < 32) {                                                          \
            float dx_ = pax - pbx, dy_ = pay - pby, dz_ = paz - pbz;           \
            dx_ *= dx_; dy_ *= dy_; dz_ *= dz_;                                \
            dist_l[BUF][t] = sqrtf(dx_ * dx_ + dy_ * dy_ + dz_ * dz_);         \
            dst_l[BUF][t] = sdst;                                              \
        }                                                                      \
    } while (0)

    int tile = blockIdx.x;
    EDGE_ISSUE(tile);
    int buf = 0;

    while (true) {
        EDGE_COMMIT(buf);
        __syncthreads();                                  // B1: a_sh ready
        int next = tile + gridDim.x;
        if (next < n_tiles) EDGE_ISSUE(next);

        // ---- GEMM1 (swapped): D[n][e], K=256 ----
        {
            f32x4 acc[2][2] = {};
#pragma unroll
            for (int i = 0; i < 8; ++i) {
                int kb = i * 64 + l4g * 16;
                bfrag be0 = *(const bfrag*)((const char*)a_sh[buf] +
                            ((unsigned)(l16 * 512 + kb) ^ swz));
                bfrag be1 = *(const bfrag*)((const char*)a_sh[buf] +
                            ((unsigned)((16 + l16) * 512 + kb) ^ swz));
                acc[0][0] = __builtin_amdgcn_mfma_f32_16x16x32_bf16(wa10[i], be0, acc[0][0], 0, 0, 0);
                acc[0][1] = __builtin_amdgcn_mfma_f32_16x16x32_bf16(wa10[i], be1, acc[0][1], 0, 0, 0);
                acc[1][0] = __builtin_amdgcn_mfma_f32_16x16x32_bf16(wa11[i], be0, acc[1][0], 0, 0, 0);
                acc[1][1] = __builtin_amdgcn_mfma_f32_16x16x32_bf16(wa11[i], be1, acc[1][1], 0, 0, 0);
            }
            float de0 = dist_l[buf][l16];
            float de1 = dist_l[buf][16 + l16];
#pragma unroll
            for (int mi = 0; mi < 2; ++mi)
#pragma unroll
                for (int ni = 0; ni < 2; ++ni) {
                    float de = ni ? de1 : de0;
                    u16x4 pk;
#pragma unroll
                    for (int rg = 0; rg < 4; ++rg) {
                        float v = fast_tanh(acc[mi][ni][rg] + de * w1l_r[mi][rg] + b1_r[mi][rg]);
                        pk[rg] = f2b(v);
                    }
                    unsigned byte = ((unsigned)((16 * ni + l16) * 256 +
                                     (32 * w + 16 * mi + l4g * 4) * 2)) ^ swz;
                    *(u16x4*)((char*)m1_sh + byte) = pk;
                }
        }
        __syncthreads();                                  // B2: m1 ready

        // ---- GEMM2 (swapped): D[n][e], K=128 -> direct global store of m_ij ----
        {
            f32x4 acc[2][2] = {};
#pragma unroll
            for (int i = 0; i < 4; ++i) {
                int kb = i * 64 + l4g * 16;
                bfrag me0 = *(const bfrag*)((const char*)m1_sh +
                            ((unsigned)(l16 * 256 + kb) ^ swz));
                bfrag me1 = *(const bfrag*)((const char*)m1_sh +
                            ((unsigned)((16 + l16) * 256 + kb) ^ swz));
                acc[0][0] = __builtin_amdgcn_mfma_f32_16x16x32_bf16(w2f0[i], me0, acc[0][0], 0, 0, 0);
                acc[0][1] = __builtin_amdgcn_mfma_f32_16x16x32_bf16(w2f0[i], me1, acc[0][1], 0, 0, 0);
                acc[1][0] = __builtin_amdgcn_mfma_f32_16x16x32_bf16(w2f1[i], me0, acc[1][0], 0, 0, 0);
                acc[1][1] = __builtin_amdgcn_mfma_f32_16x16x32_bf16(w2f1[i], me1, acc[1][1], 0, 0, 0);
            }
            int dr0 = dst_l[buf][l16];
            int dr1 = dst_l[buf][16 + l16];
#pragma unroll
            for (int mi = 0; mi < 2; ++mi)
#pragma unroll
                for (int ni = 0; ni < 2; ++ni) {
                    u16x4 pk;
#pragma unroll
                    for (int rg = 0; rg < 4; ++rg)
                        pk[rg] = f2b(fast_tanh(acc[mi][ni][rg] + b2_r[mi][rg]));
                    int dstrow = ni ? dr1 : dr0;
                    u16* dp = g + (size_t)dstrow * 128 + (32 * w + 16 * mi + l4g * 4);
                    *(u16x4*)dp = pk;
                }
        }

        tile = next; buf ^= 1;
        if (tile >= n_tiles) break;
    }
#undef EDGE_ISSUE
#undef EDGE_COMMIT
}

// ---------------- gather + gate: m_i[n] = sum_e tanh(fw.m_e + fb) * m_e ----------------
__global__ void __launch_bounds__(256, 8)
gather_gate(const u16* __restrict__ g, const int* __restrict__ offs,
            const float* __restrict__ fw, const float* __restrict__ fb,
            u16* __restrict__ m_i)
{
    const int lane = threadIdx.x & 63;
    const int n = blockIdx.x * 4 + (threadIdx.x >> 6);
    const float fw0 = fw[2 * lane], fw1 = fw[2 * lane + 1];
    const float fbv = fb[0];
    const int beg = offs[n], end = offs[n + 1];
    const unsigned* g32 = (const unsigned*)g;
    float a0 = 0.0f, a1 = 0.0f;
    int e = beg;
    for (; e + 1 < end; e += 2) {
        unsigned v0 = g32[(size_t)e * 64 + lane];
        unsigned v1 = g32[(size_t)(e + 1) * 64 + lane];
        float f00 = bits2f(v0 << 16), f01 = bits2f(v0 & 0xFFFF0000u);
        float f10 = bits2f(v1 << 16), f11 = bits2f(v1 & 0xFFFF0000u);
        float s0 = f00 * fw0 + f01 * fw1;
        float s1 = f10 * fw0 + f11 * fw1;
#pragma unroll
        for (int m = 1; m < 64; m <<= 1) {
            s0 += __shfl_xor(s0, m);
            s1 += __shfl_xor(s1, m);
        }
        float ev0 = fast_tanh(s0 + fbv);
        float ev1 = fast_tanh(s1 + fbv);
        a0 += ev0 * f00 + ev1 * f10;
        a1 += ev0 * f01 + ev1 * f11;
    }
    if (e < end) {
        unsigned v0 = g32[(size_t)e * 64 + lane];
        float f00 = bits2f(v0 << 16), f01 = bits2f(v0 & 0xFFFF0000u);
        float s0 = f00 * fw0 + f01 * fw1;
#pragma unroll
        for (int m = 1; m < 64; m <<= 1) s0 += __shfl_xor(s0, m);
        float ev0 = fast_tanh(s0 + fbv);
        a0 += ev0 * f00;
        a1 += ev0 * f01;
    }
    unsigned o = (unsigned)f2b(a0) | ((unsigned)f2b(a1) << 16);
    ((unsigned*)m_i)[(size_t)n * 64 + lane] = o;
}

// ---------------- edge kernel, fallback atomic path (round-3, proven) ----------------
__global__ void __launch_bounds__(256, 3)
egc_edge_mfma(const u16* __restrict__ xb, const float* __restrict__ pos,
              const int* __restrict__ est, const int* __restrict__ eend,
              const u16* __restrict__ w1t, const float* __restrict__ w1last,
              const float* __restrict__ b1, const u16* __restrict__ w2t,
              const float* __restrict__ b2, const float* __restrict__ fw,
              const float* __restrict__ fb, float* __restrict__ m_i)
{
    __shared__ __attribute__((aligned(16))) u16 a_sh[32 * 256];
    __shared__ __attribute__((aligned(16))) u16 m1_sh[32 * 128];
    __shared__ float m2_sh[32][132];
    __shared__ float dist_l[32];
    __shared__ float ev_l[32];
    __shared__ int   st_l[32];

    const int t = threadIdx.x;
    const int e0 = blockIdx.x * 32;
    const int lane = t & 63;
    const int w = t >> 6;
    const int l16 = lane & 15, l4g = lane >> 4;

#pragma unroll
    for (int i = 0; i < 4; ++i) {
        int f = t + 256 * i;
        int e = f >> 5, q = f & 31;
        int ge = e0 + e;
        int node = (q < 16) ? est[ge] : eend[ge];
        float4 v = *(const float4*)(xb + (size_t)node * 128 + (q & 15) * 8);
        unsigned byte = (unsigned)(e * 512 + q * 16) ^ (unsigned)((e & 7) << 4);
        *(float4*)((char*)a_sh + byte) = v;
    }
    if (t < 32) {
        int ge = e0 + t;
        int a = est[ge], b = eend[ge];
        st_l[t] = a;
        float dx = pos[a * 3 + 0] - pos[b * 3 + 0];
        float dy = pos[a * 3 + 1] - pos[b * 3 + 1];
        float dz = pos[a * 3 + 2] - pos[b * 3 + 2];
        dx *= dx; dy *= dy; dz *= dz;
        dist_l[t] = sqrtf(dx * dx + dy * dy + dz * dz);
    }
    __syncthreads();

    {
        f32x4 acc[2][2] = {};
        gemm_k<256>(a_sh, w1t, w, l16, l4g, acc);
#pragma unroll
        for (int mi = 0; mi < 2; ++mi)
#pragma unroll
            for (int ni = 0; ni < 2; ++ni) {
                const int col = 32 * w + 16 * ni + l16;
                const float wl = w1last[col], bb = b1[col];
#pragma unroll
                for (int rg = 0; rg < 4; ++rg) {
                    const int row = 16 * mi + l4g * 4 + rg;
                    float v = fast_tanh(acc[mi][ni][rg] + dist_l[row] * wl + bb);
                    unsigned byte = (unsigned)((row * 256 + col * 2) ^ ((row & 7) << 4));
                    *(u16*)((char*)m1_sh + byte) = f2b(v);
                }
            }
    }
    __syncthreads();

    {
        f32x4 acc[2][2] = {};
        gemm_k<128>(m1_sh, w2t, w, l16, l4g, acc);
#pragma unroll
        for (int mi = 0; mi < 2; ++mi)
#pragma unroll
            for (int ni = 0; ni < 2; ++ni) {
                const int col = 32 * w + 16 * ni + l16;
                const float bb = b2[col];
#pragma unroll
                for (int rg = 0; rg < 4; ++rg) {
                    const int row = 16 * mi + l4g * 4 + rg;
                    m2_sh[row][col] = fast_tanh(acc[mi][ni][rg] + bb);
                }
            }
    }
    __syncthreads();

    if (t < 128) {
        int e = t >> 2, p = t & 3;
        float s = 0.0f;
#pragma unroll
        for (int k = 0; k < 32; ++k) s += m2_sh[e][p * 32 + k] * fw[p * 32 + k];
        s += __shfl_xor(s, 1);
        s += __shfl_xor(s, 2);
        if (p == 0) ev_l[e] = fast_tanh(s + fb[0]);
    }
    __syncthreads();

    {
        int e = t >> 3, l8 = t & 7;
        float ev = ev_l[e];
        size_t base = (size_t)st_l[e] * HID + l8;
#pragma unroll
        for (int i = 0; i < 16; ++i)
            unsafeAtomicAdd(m_i + base + 8 * i, ev * m2_sh[e][l8 + 8 * i]);
    }
}

// ---------------- node kernel ----------------
#define NODE_LAYER(SRC, KD, WT, BIAS, EPILOG)                                  \
    {                                                                          \
        f32x4 acc[2][2] = {};                                                  \
        gemm_k<KD>(SRC, WT, w, l16, l4g, acc);                                 \
        _Pragma("unroll")                                                      \
        for (int mi = 0; mi < 2; ++mi)                                         \
            _Pragma("unroll")                                                  \
            for (int ni = 0; ni < 2; ++ni) {                                   \
                const int col = 32 * w + 16 * ni + l16;                        \
                const float bb = (BIAS)[col];                                  \
                _Pragma("unroll")                                              \
                for (int rg = 0; rg < 4; ++rg) {                               \
                    const int row = 16 * mi + l4g * 4 + rg;                    \
                    float v = acc[mi][ni][rg] + bb;                            \
                    EPILOG;                                                    \
                }                                                              \
            }                                                                  \
    }

#define STORE_BF16(DST) do {                                                   \
        unsigned byte = (unsigned)((row * 256 + col * 2) ^ ((row & 7) << 4));  \
        *(u16*)((char*)(DST) + byte) = f2b(v);                                 \
    } while (0)

template<bool MIBF16>
__global__ void __launch_bounds__(256, 3)
egc_node_mfma(const u16* __restrict__ xb, const float* __restrict__ xf,
              const void* __restrict__ m_i,
              const u16* __restrict__ fh1t, const float* __restrict__ hb1,
              const u16* __restrict__ fh2t, const float* __restrict__ hb2,
              const u16* __restrict__ l1t, const float* __restrict__ l1b,
              const u16* __restrict__ l2t, const float* __restrict__ l2b,
              const u16* __restrict__ l3t, const float* __restrict__ l3b,
              const u16* __restrict__ l4t, const float* __restrict__ l4b,
              const float* __restrict__ l5w, const float* __restrict__ l5b,
              float* __restrict__ out)
{
    __shared__ __attribute__((aligned(16))) u16 a_sh[32 * 256];
    __shared__ __attribute__((aligned(16))) u16 bA[32 * 128];
    __shared__ __attribute__((aligned(16))) u16 bB[32 * 128];
    __shared__ float ff[32][132];

    const int t = threadIdx.x;
    const int n0 = blockIdx.x * 32;
    const int lane = t & 63;
    const int w = t >> 6;
    const int l16 = lane & 15, l4g = lane >> 4;

#pragma unroll
    for (int i = 0; i < 2; ++i) {
        int f = t + 256 * i;
        int n = f >> 4, q = f & 15;
        float4 v = *(const float4*)(xb + (size_t)(n0 + n) * 128 + q * 8);
        unsigned byte = (unsigned)((n * 512 + q * 16) ^ ((n & 7) << 4));
        *(float4*)((char*)a_sh + byte) = v;
    }
    if (MIBF16) {
#pragma unroll
        for (int i = 0; i < 2; ++i) {
            int f = t + 256 * i;
            int n = f >> 4, q = f & 15;
            float4 v = *(const float4*)((const u16*)m_i + (size_t)(n0 + n) * 128 + q * 8);
            unsigned byte = (unsigned)((n * 512 + 256 + q * 16) ^ ((n & 7) << 4));
            *(float4*)((char*)a_sh + byte) = v;
        }
    } else {
#pragma unroll
        for (int i = 0; i < 2; ++i) {
            int f = t + 256 * i;
            int n = f >> 4, q = f & 15;
            const float* src = (const float*)m_i + (size_t)(n0 + n) * 128 + q * 8;
            float4 v0 = *(const float4*)(src);
            float4 v1 = *(const float4*)(src + 4);
            u16x8 o = { f2b(v0.x), f2b(v0.y), f2b(v0.z), f2b(v0.w),
                        f2b(v1.x), f2b(v1.y), f2b(v1.z), f2b(v1.w) };
            unsigned byte = (unsigned)((n * 512 + 256 + q * 16) ^ ((n & 7) << 4));
            *(u16x8*)((char*)a_sh + byte) = o;
        }
    }
    __syncthreads();

    NODE_LAYER(a_sh, 256, fh1t, hb1, { v = fast_tanh(v); STORE_BF16(bA); })
    __syncthreads();
    NODE_LAYER(bA, 128, fh2t, hb2,
               { v += xf[(size_t)(n0 + row) * HID + col]; STORE_BF16(bB); })
    __syncthreads();
    NODE_LAYER(bB, 128, l1t, l1b, { v = v > 0.0f ? v : 0.01f * v; STORE_BF16(bA); })
    __syncthreads();
    NODE_LAYER(bA, 128, l2t, l2b, { v = v > 0.0f ? v : 0.01f * v; STORE_BF16(bB); })
    __syncthreads();
    NODE_LAYER(bB, 128, l3t, l3b, { v = v > 0.0f ? v : 0.01f * v; STORE_BF16(bA); })
    __syncthreads();
    NODE_LAYER(bA, 128, l4t, l4b, { ff[row][col] = v > 0.0f ? v : 0.01f * v; })
    __syncthreads();

    if (t < 96) {
        int n = t / 3, cc = t % 3;
        float s = l5b[cc];
#pragma unroll 8
        for (int k = 0; k < HID; ++k) s += ff[n][k] * l5w[k * 3 + cc];
        out[(size_t)(n0 + n) * 3 + cc] = s;
    }
}

extern "C" void kernel_launch(void* const* d_in, const int* in_sizes, int n_in,
                              void* d_out, int out_size, void* d_ws, size_t ws_size,
                              hipStream_t stream)
{
    const float* x      = (const float*)d_in[0];
    const float* pos    = (const float*)d_in[1];
    const int*   eidx   = (const int*)d_in[2];
    const float* fe_w1  = (const float*)d_in[3];
    const float* fe_b1  = (const float*)d_in[4];
    const float* fe_w2  = (const float*)d_in[5];
    const float* fe_b2  = (const float*)d_in[6];
    const float* finf_w = (const float*)d_in[7];
    const float* finf_b = (const float*)d_in[8];
    const float* fh_w1  = (const float*)d_in[9];
    const float* fh_b1  = (const float*)d_in[10];
    const float* fh_w2  = (const float*)d_in[11];
    const float* fh_b2  = (const float*)d_in[12];
    const float* l1w    = (const float*)d_in[13];
    const float* l1b    = (const float*)d_in[14];
    const float* l2w    = (const float*)d_in[15];
    const float* l2b    = (const float*)d_in[16];
    const float* l3w    = (const float*)d_in[17];
    const float* l3b    = (const float*)d_in[18];
    const float* l4w    = (const float*)d_in[19];
    const float* l4b    = (const float*)d_in[20];
    const float* l5w    = (const float*)d_in[21];
    const float* l5b    = (const float*)d_in[22];
    float* out = (float*)d_out;

    const int n_edges = in_sizes[2] / 2;             // 600000
    const int n_nodes = in_sizes[0] / HID;           // 100000
    const int nsb     = (n_nodes + 255) / 256;       // 391 scan blocks
    const int n_tiles = n_edges / 32;                // 18750

    char* ws = (char*)d_ws;
    const bool use_csr = (ws_size >= 208800000ULL);

    if (use_csr) {
        u16* g    = (u16*)(ws + 0);                  // 153,600,000 B
        u16* xb   = (u16*)(ws + 153600000);          //  25,600,000 B
        u16* m_i  = (u16*)(ws + 179200000);          //  25,600,000 B (bf16)
        u16* w1t  = (u16*)(ws + 204800000);
        u16* w2t  = (u16*)(ws + 204865536);
        u16* fh1t = (u16*)(ws + 204898304);
        u16* fh2t = (u16*)(ws + 204963840);
        u16* l1t  = (u16*)(ws + 204996608);
        u16* l2t  = (u16*)(ws + 205029376);
        u16* l3t  = (u16*)(ws + 205062144);
        u16* l4t  = (u16*)(ws + 205094912);
        int* cnt  = (int*)(ws + 205127680);          // 400,000 B
        int* offs = (int*)(ws + 205527680);          // 400,016 B (N+1 ints)
        int* cur  = (int*)(ws + 205927696);          // 400,000 B
        int* inv  = (int*)(ws + 206327696);          // 2,400,000 B
        int* part = (int*)(ws + 208727696);          // scan partials

        (void)hipMemsetAsync(cnt, 0, (size_t)n_nodes * sizeof(int), stream);
        prep_x<<<dim3((n_nodes * HID) / (256 * 8)), dim3(256), 0, stream>>>(x, xb);
        prep_weights<<<dim3(640), dim3(256), 0, stream>>>(
            fe_w1, fh_w1, fe_w2, fh_w2, l1w, l2w, l3w, l4w,
            w1t, fh1t, w2t, fh2t, l1t, l2t, l3t, l4t);

        hist_kernel<<<dim3((n_edges + 255) / 256), dim3(256), 0, stream>>>(eidx, cnt, n_edges);
        scan1<<<dim3(nsb), dim3(256), 0, stream>>>(cnt, cnt, part, n_nodes);
        scan2<<<dim3(1), dim3(512), 0, stream>>>(part, nsb);
        scan3<<<dim3(nsb), dim3(256), 0, stream>>>(cnt, part, offs, cur, n_nodes, n_edges);
        reorder_kernel<<<dim3((n_edges + 255) / 256), dim3(256), 0, stream>>>(eidx, cur, inv, n_edges);

        egc_edge_csr<<<dim3(512), dim3(256), 0, stream>>>(
            xb, pos, eidx, eidx + n_edges, inv, w1t, fe_w1 + (size_t)256 * HID, fe_b1,
            w2t, fe_b2, g, n_tiles);

        gather_gate<<<dim3(n_nodes / 4), dim3(256), 0, stream>>>(g, offs, finf_w, finf_b, m_i);

        egc_node_mfma<true><<<dim3(n_nodes / 32), dim3(256), 0, stream>>>(
            xb, x, m_i, fh1t, fh_b1, fh2t, fh_b2, l1t, l1b, l2t, l2b,
            l3t, l3b, l4t, l4b, l5w, l5b, out);
    } else {
        // fallback: round-3 fused atomic path
        float* m_i = (float*)(ws + 0);
        u16* xb    = (u16*)(ws + 51200000);
        u16* w1t   = (u16*)(ws + 76800000);
        u16* w2t   = (u16*)(ws + 76865536);
        u16* fh1t  = (u16*)(ws + 76898304);
        u16* fh2t  = (u16*)(ws + 76963840);
        u16* l1t   = (u16*)(ws + 76996608);
        u16* l2t   = (u16*)(ws + 77029376);
        u16* l3t   = (u16*)(ws + 77062144);
        u16* l4t   = (u16*)(ws + 77094912);

        (void)hipMemsetAsync(m_i, 0, (size_t)n_nodes * HID * sizeof(float), stream);
        prep_x<<<dim3((n_nodes * HID) / (256 * 8)), dim3(256), 0, stream>>>(x, xb);
        prep_weights<<<dim3(640), dim3(256), 0, stream>>>(
            fe_w1, fh_w1, fe_w2, fh_w2, l1w, l2w, l3w, l4w,
            w1t, fh1t, w2t, fh2t, l1t, l2t, l3t, l4t);

        egc_edge_mfma<<<dim3(n_edges / 32), dim3(256), 0, stream>>>(
            xb, pos, eidx, eidx + n_edges, w1t, fe_w1 + (size_t)256 * HID, fe_b1,
            w2t, fe_b2, finf_w, finf_b, m_i);

        egc_node_mfma<false><<<dim3(n_nodes / 32), dim3(256), 0, stream>>>(
            xb, x, m_i, fh1t, fh_b1, fh2t, fh_b2, l1t, l1b, l2t, l2b,
            l3t, l3b, l4t, l4b, l5w, l5b, out);
    }
}